// Round 11
// baseline (418.986 us; speedup 1.0000x reference)
//
#include <hip/hip_runtime.h>

// Problem constants: B=8, M=N=256, D=512
#define INFV 1.0e8f

// Raw HW transcendentals: v_exp_f32 is 2^x, v_log_f32 is log2(x).
#define EXP2F(x) __builtin_amdgcn_exp2f(x)
#define LOG2F(x) __builtin_amdgcn_logf(x)
#define MED3F(a,b,c) __builtin_amdgcn_fmed3f(a,b,c)

__device__ __forceinline__ void ld4(float d[4], const float* p) {
  float4 v = *(const float4*)p;
  d[0] = v.x; d[1] = v.y; d[2] = v.z; d[3] = v.w;
}

// softmin in the q = R*(log2e/gv) domain; one exp2 arg is exactly 0:
//   softmin(a,b,c) = mn - log2(1 + exp2(mn-med) + exp2(mn-max))
__device__ __forceinline__ float softmin3(float a, float b, float c) {
  float mn = fminf(fminf(a, b), c);
  float md = MED3F(a, b, c);
  float mx = fmaxf(fmaxf(a, b), c);
  return mn - LOG2F(1.0f + EXP2F(mn - md) + EXP2F(mn - mx));
}

// ---------------------------------------------------------------------------
// Kernel 1: inverse row norms.  rn = 1 / max(||row||, 1e-8)
// ---------------------------------------------------------------------------
__global__ void __launch_bounds__(256) norms_kernel(const float* __restrict__ x,
                                                    const float* __restrict__ y,
                                                    float* __restrict__ rnx,
                                                    float* __restrict__ rny) {
  int g = blockIdx.x * 4 + (threadIdx.x >> 6);
  int lane = threadIdx.x & 63;
  const float* src; float* dst; int row;
  if (g < 2048) { src = x; dst = rnx; row = g; }
  else          { src = y; dst = rny; row = g - 2048; }
  const float* p = src + (size_t)row * 512;
  float4 v0 = *(const float4*)(p + lane * 4);
  float4 v1 = *(const float4*)(p + 256 + lane * 4);
  float s = v0.x*v0.x + v0.y*v0.y + v0.z*v0.z + v0.w*v0.w
          + v1.x*v1.x + v1.y*v1.y + v1.z*v1.z + v1.w*v1.w;
#pragma unroll
  for (int o = 32; o > 0; o >>= 1) s += __shfl_xor(s, o, 64);
  if (lane == 0) dst[row] = 1.0f / fmaxf(sqrtf(s), 1e-8f);
}

// ---------------------------------------------------------------------------
// Kernel 2: cost GEMM -> ROW-MAJOR costR[b][m][n], PRE-SCALED by ig2=log2e/gv.
// ---------------------------------------------------------------------------
__global__ void __launch_bounds__(256) cost_gemm(const float* __restrict__ x,
                                                 const float* __restrict__ y,
                                                 const float* __restrict__ rnx,
                                                 const float* __restrict__ rny,
                                                 const float* __restrict__ gamma,
                                                 float* __restrict__ costR) {
  int b = blockIdx.z, mt = blockIdx.y, nt = blockIdx.x;
  int m0 = mt * 64, n0 = nt * 64;
  __shared__ float Xs[16][68];
  __shared__ float Ys[16][68];
  int tid = threadIdx.x;
  int row = tid >> 2, cq = tid & 3;
  int tx = tid & 15, ty = tid >> 4;
  const float* xb = x + ((size_t)b * 256 + m0) * 512;
  const float* yb = y + ((size_t)b * 256 + n0) * 512;
  float acc[4][4] = {};
  for (int k0 = 0; k0 < 512; k0 += 16) {
    float4 xv = *(const float4*)(xb + (size_t)row * 512 + k0 + cq * 4);
    float4 yv = *(const float4*)(yb + (size_t)row * 512 + k0 + cq * 4);
    __syncthreads();
    Xs[cq*4+0][row] = xv.x; Xs[cq*4+1][row] = xv.y;
    Xs[cq*4+2][row] = xv.z; Xs[cq*4+3][row] = xv.w;
    Ys[cq*4+0][row] = yv.x; Ys[cq*4+1][row] = yv.y;
    Ys[cq*4+2][row] = yv.z; Ys[cq*4+3][row] = yv.w;
    __syncthreads();
#pragma unroll
    for (int kk = 0; kk < 16; ++kk) {
      float4 av = *(const float4*)(&Xs[kk][ty * 4]);
      float4 bv = *(const float4*)(&Ys[kk][tx * 4]);
      float ar[4] = {av.x, av.y, av.z, av.w};
      float br[4] = {bv.x, bv.y, bv.z, bv.w};
#pragma unroll
      for (int r = 0; r < 4; ++r)
#pragma unroll
        for (int c = 0; c < 4; ++c)
          acc[r][c] += ar[r] * br[c];
    }
  }
  float gv = fmaxf(fabsf(gamma[0]), 1e-4f);
  float ig2 = 1.4426950408889634f / gv;
  float rx[4], ry[4];
#pragma unroll
  for (int r = 0; r < 4; ++r) rx[r] = rnx[b * 256 + m0 + ty * 4 + r];
#pragma unroll
  for (int c = 0; c < 4; ++c) ry[c] = rny[b * 256 + n0 + tx * 4 + c];
  float* cbb = costR + (size_t)b * 65536;
#pragma unroll
  for (int r = 0; r < 4; ++r) {
    int m = m0 + ty * 4 + r;
    float4 st = {(1.0f - acc[r][0] * rx[r] * ry[0]) * ig2,
                 (1.0f - acc[r][1] * rx[r] * ry[1]) * ig2,
                 (1.0f - acc[r][2] * rx[r] * ry[2]) * ig2,
                 (1.0f - acc[r][3] * rx[r] * ry[3]) * ig2};
    *(float4*)(cbb + (size_t)m * 256 + n0 + tx * 4) = st;
  }
}

// ---------------------------------------------------------------------------
// Kernel 3: forward soft-DTW, ROW-STRIP.  ONE 512-thread block; wave w =
// batch w.  8 waves -> 2 per SIMD: two independent in-order streams per SIMD
// so one batch's dependence stalls are filled by the other's instructions.
// Lane l owns COLUMNS 4l..4l+3, walks rows top->bottom, skewed (lane l does
// row r at slot s = r + l).  Per slot: ONE shfl_up, a 4-cell chain, one
// coalesced float4 cost load (3-deep FIFO), one coalesced float4 q store.
// No LDS, no barriers (waves never communicate).
// ---------------------------------------------------------------------------
__global__ void __launch_bounds__(512, 1) fwd_kernel(const float* __restrict__ costR,
                                                     const float* __restrict__ gamma,
                                                     float* __restrict__ qR,
                                                     float* __restrict__ dist_out) {
  int t = threadIdx.x;
  int b = t >> 6, l = t & 63;
  float gv = fmaxf(fabsf(gamma[0]), 1e-4f);
  float gl = gv * 0.6931471805599453f;      // R = q * gl
  const float* cb = costR + (size_t)b * 65536 + 4 * l;
  float* qb = qR + (size_t)b * 65536 + 4 * l;
  float ub0 = INFV, ub1 = INFV, ub2 = INFV, ub3 = INFV;  // q[r-1][4l+k]
  float o3 = INFV;                           // my last row's col 4l+3
  float ucar = (l == 0) ? 0.0f : INFV;       // q[r-1][4l-1]; (0,0) diag seed
  float A0[4], A1[4], A2[4];
  auto loadC = [&](int s, float* buf) {
    int r = s - l; r = r < 0 ? 0 : (r > 255 ? 255 : r);
    ld4(buf, cb + (size_t)r * 256);
  };
  auto body = [&](int s, const float* cc) {
    int r = s - l;
    bool act = (unsigned)r <= 255u;
    float li = __shfl_up(o3, 1);     // q[r][4l-1] (lane l-1, one slot behind)
    if (l == 0) li = INFV;
    float v0 = cc[0] + softmin3(ub0, li, ucar);
    float v1 = cc[1] + softmin3(ub1, v0, ub0);
    float v2 = cc[2] + softmin3(ub2, v1, ub1);
    float v3 = cc[3] + softmin3(ub3, v2, ub2);
    if (act) {
      float4 st = {v0, v1, v2, v3};
      *(float4*)(qb + (size_t)r * 256) = st;
      ub0 = v0; ub1 = v1; ub2 = v2; ub3 = v3;
      o3 = v3; ucar = li;
      if (l == 63 && r == 255) dist_out[b] = v3 * gl;
    }
  };
  loadC(0, A0); loadC(1, A1); loadC(2, A2);
  for (int it = 0; it < 107; ++it) {   // 321 slots; last live slot = 318
    int s = it * 3;
    body(s + 0, A0); loadC(s + 3, A0);
    body(s + 1, A1); loadC(s + 4, A1);
    body(s + 2, A2); loadC(s + 5, A2);
  }
}

// ---------------------------------------------------------------------------
// Kernel 3.5: backward weights, PACKED: record[(b*256+r)*64+l] = 16 floats
// (wd[0..3], wn[0..3], wr[0..3], pad) = one aligned 64 B line per (row,lane).
// Boundary masking folded in (w=0).  Reads/writes fully coalesced.
// ---------------------------------------------------------------------------
__global__ void __launch_bounds__(256) weights_kernel(const float* __restrict__ qR,
                                                      const float* __restrict__ costR,
                                                      float* __restrict__ W3) {
  int tid = blockIdx.x * 256 + threadIdx.x;   // = ((b*256 + r)*64 + l)
  int l = tid & 63;
  int r = (tid >> 6) & 255;
  int b = tid >> 14;
  const float* qb = qR + (size_t)b * 65536;
  const float* cbb = costR + (size_t)b * 65536;
  int rp = min(r + 1, 255);
  int c0i = 4 * l;
  int c4 = min(c0i + 4, 255);
  float q0a[5], q1a[5], c0a[5], c1a[5];
  ld4(q0a, qb + (size_t)r * 256 + c0i);  q0a[4] = qb[(size_t)r * 256 + c4];
  ld4(q1a, qb + (size_t)rp * 256 + c0i); q1a[4] = qb[(size_t)rp * 256 + c4];
  ld4(c0a, cbb + (size_t)r * 256 + c0i);  c0a[4] = cbb[(size_t)r * 256 + c4];
  ld4(c1a, cbb + (size_t)rp * 256 + c0i); c1a[4] = cbb[(size_t)rp * 256 + c4];
  const float CL = 50.0f * 1.4426950408889634f;
  bool rm = (r < 255);
  float w[16];
#pragma unroll
  for (int k = 0; k < 4; ++k) {
    bool cm = (c0i + k < 255);
    float ad = fminf(fmaxf((q1a[k+1] - c1a[k+1]) - q0a[k], -CL), CL);
    float an = fminf(fmaxf((q1a[k]   - c1a[k])   - q0a[k], -CL), CL);
    float ar = fminf(fmaxf((q0a[k+1] - c0a[k+1]) - q0a[k], -CL), CL);
    w[k]      = (rm && cm) ? EXP2F(ad) : 0.0f;
    w[4 + k]  = rm ? EXP2F(an) : 0.0f;
    w[8 + k]  = cm ? EXP2F(ar) : 0.0f;
    w[12 + k] = 0.0f;
  }
  float* wp = W3 + (size_t)tid * 16;
#pragma unroll
  for (int j = 0; j < 4; ++j) *(float4*)(wp + 4 * j) = *(float4*)(w + 4 * j);
}

// ---------------------------------------------------------------------------
// Kernel 4: backward recurrence, ROW-STRIP mirrored: lane l owns cols
// 4l..4l+3, walks rows bottom->top; lane l does row r at slot s = 318-r-l
// (lane 63 leads).  Per slot: ONE shfl_down, 12 FMAs, one 64 B packed-weight
// record via a 6-DEEP FIFO, one float4 E store DIRECTLY to d_out.
// Stays at 8 blocks x 64 (one CU per batch): 5 KB/slot/wave of weight
// traffic would hit a ~640 cyc/slot L1-BW floor if co-located on one CU.
//   E[r][c] = E[r+1][c+1]*wd + E[r+1][c]*wn + E[r][c+1]*wr,  E[255][255]=1.
// ---------------------------------------------------------------------------
__global__ void __launch_bounds__(64, 1) bwd_kernel(const float* __restrict__ W3,
                                                    float* __restrict__ out) {
  int b = blockIdx.x, l = threadIdx.x;
  const float* wb = W3 + ((size_t)b * 16384 + l) * 16;   // + r*1024
  float* ob = out + (size_t)b * 65536 + 4 * l;
  float db0 = 0.f, db1 = 0.f, db2 = 0.f, db3 = 0.f;  // E[r+1][4l+k]
  float o0 = 0.f;       // my last row's col 4l value
  float dcar = 0.f;     // E[r+1][4l+4]
  float F0[16], F1[16], F2[16], F3[16], F4[16], F5[16];
  auto loadW = [&](int s, float* buf) {
    int r = 318 - s - l; r = r < 0 ? 0 : (r > 255 ? 255 : r);
    const float* p = wb + (size_t)r * 1024;
    ld4(buf, p); ld4(buf + 4, p + 4); ld4(buf + 8, p + 8); ld4(buf + 12, p + 12);
  };
  auto body = [&](int s, const float* w) {
    int r = 318 - s - l;
    bool act = (unsigned)r <= 255u;
    float ri = __shfl_down(o0, 1);   // E[r][4l+4] (lane l+1, one slot behind)
    if (l == 63) ri = 0.0f;
    float v3 = w[3] * dcar + w[7] * db3 + w[11] * ri;
    if (l == 63 && r == 255) v3 = 1.0f;     // seed E[255][255]
    float v2 = w[2] * db3 + w[6] * db2 + w[10] * v3;
    float v1 = w[1] * db2 + w[5] * db1 + w[9]  * v2;
    float v0 = w[0] * db1 + w[4] * db0 + w[8]  * v1;
    if (act) {
      float4 st = {v0, v1, v2, v3};
      *(float4*)(ob + (size_t)r * 256) = st;
      db0 = v0; db1 = v1; db2 = v2; db3 = v3;
      o0 = v0; dcar = ri;
    }
  };
  loadW(0, F0); loadW(1, F1); loadW(2, F2);
  loadW(3, F3); loadW(4, F4); loadW(5, F5);
  for (int it = 0; it < 54; ++it) {   // 324 slots; last live slot = 318
    int s = it * 6;
    body(s + 0, F0); loadW(s + 6,  F0);
    body(s + 1, F1); loadW(s + 7,  F1);
    body(s + 2, F2); loadW(s + 8,  F2);
    body(s + 3, F3); loadW(s + 9,  F3);
    body(s + 4, F4); loadW(s + 10, F4);
    body(s + 5, F5); loadW(s + 11, F5);
  }
}

// ---------------------------------------------------------------------------
// Workspace (floats), ~12.6 MB:
//   rnx @ 0 (2048) | rny @ 2048 (2048)
//   costR @ 4096        (8*65536, row-major, pre-scaled by ig2)
//   qR    @ +524288     (8*65536, row-major)
//   W3    @ +524288     (8*256*64*16 = 2,097,152: packed 64 B weight records)
// Alignment (E) goes straight into d_out from bwd_kernel.
// d_out: alignment [0 .. 524287], distance [524288 .. 524295].
// ---------------------------------------------------------------------------
extern "C" void kernel_launch(void* const* d_in, const int* in_sizes, int n_in,
                              void* d_out, int out_size, void* d_ws, size_t ws_size,
                              hipStream_t stream) {
  const float* x = (const float*)d_in[0];
  const float* y = (const float*)d_in[1];
  const float* gamma = (const float*)d_in[2];
  float* out = (float*)d_out;
  float* ws = (float*)d_ws;

  const size_t MAT = (size_t)8 * 65536;
  float* rnx   = ws;
  float* rny   = ws + 2048;
  float* costR = ws + 4096;
  float* qR    = costR + MAT;
  float* W3    = qR + MAT;

  norms_kernel<<<1024, 256, 0, stream>>>(x, y, rnx, rny);
  cost_gemm<<<dim3(4, 4, 8), 256, 0, stream>>>(x, y, rnx, rny, gamma, costR);
  fwd_kernel<<<1, 512, 0, stream>>>(costR, gamma, qR, out + 524288);
  weights_kernel<<<512, 256, 0, stream>>>(qR, costR, W3);
  bwd_kernel<<<8, 64, 0, stream>>>(W3, out);
}

// Round 13
// 206.823 us; speedup vs baseline: 2.0258x; 2.0258x over previous
//
#include <hip/hip_runtime.h>

// Problem constants: B=8, M=N=256, D=512
#define INFV 1.0e8f

// Raw HW transcendentals: v_exp_f32 is 2^x, v_log_f32 is log2(x).
#define EXP2F(x) __builtin_amdgcn_exp2f(x)
#define LOG2F(x) __builtin_amdgcn_logf(x)

__device__ __forceinline__ void ld4(float d[4], const float* p) {
  float4 v = *(const float4*)p;
  d[0] = v.x; d[1] = v.y; d[2] = v.z; d[3] = v.w;
}

// ---------------------------------------------------------------------------
// Kernel 1: inverse row norms.  rn = 1 / max(||row||, 1e-8)
// ---------------------------------------------------------------------------
__global__ void __launch_bounds__(256) norms_kernel(const float* __restrict__ x,
                                                    const float* __restrict__ y,
                                                    float* __restrict__ rnx,
                                                    float* __restrict__ rny) {
  int g = blockIdx.x * 4 + (threadIdx.x >> 6);
  int lane = threadIdx.x & 63;
  const float* src; float* dst; int row;
  if (g < 2048) { src = x; dst = rnx; row = g; }
  else          { src = y; dst = rny; row = g - 2048; }
  const float* p = src + (size_t)row * 512;
  float4 v0 = *(const float4*)(p + lane * 4);
  float4 v1 = *(const float4*)(p + 256 + lane * 4);
  float s = v0.x*v0.x + v0.y*v0.y + v0.z*v0.z + v0.w*v0.w
          + v1.x*v1.x + v1.y*v1.y + v1.z*v1.z + v1.w*v1.w;
#pragma unroll
  for (int o = 32; o > 0; o >>= 1) s += __shfl_xor(s, o, 64);
  if (lane == 0) dst[row] = 1.0f / fmaxf(sqrtf(s), 1e-8f);
}

// ---------------------------------------------------------------------------
// Kernel 2: cost GEMM -> ROW-MAJOR.  Two outputs, both scaled by ig2=log2e/gv:
//   costR = cost*ig2              (for the weights kernel)
//   mR    = exp2(-cost*ig2)       (for the p-domain forward kernel)
// NOTE: relies on cost*ig2 staying within fp32 exp2 range (gamma=1 here;
// cosine cost in [0,2] -> exponent <= ~3).
// ---------------------------------------------------------------------------
__global__ void __launch_bounds__(256) cost_gemm(const float* __restrict__ x,
                                                 const float* __restrict__ y,
                                                 const float* __restrict__ rnx,
                                                 const float* __restrict__ rny,
                                                 const float* __restrict__ gamma,
                                                 float* __restrict__ costR,
                                                 float* __restrict__ mR) {
  int b = blockIdx.z, mt = blockIdx.y, nt = blockIdx.x;
  int m0 = mt * 64, n0 = nt * 64;
  __shared__ float Xs[16][68];
  __shared__ float Ys[16][68];
  int tid = threadIdx.x;
  int row = tid >> 2, cq = tid & 3;
  int tx = tid & 15, ty = tid >> 4;
  const float* xb = x + ((size_t)b * 256 + m0) * 512;
  const float* yb = y + ((size_t)b * 256 + n0) * 512;
  float acc[4][4] = {};
  for (int k0 = 0; k0 < 512; k0 += 16) {
    float4 xv = *(const float4*)(xb + (size_t)row * 512 + k0 + cq * 4);
    float4 yv = *(const float4*)(yb + (size_t)row * 512 + k0 + cq * 4);
    __syncthreads();
    Xs[cq*4+0][row] = xv.x; Xs[cq*4+1][row] = xv.y;
    Xs[cq*4+2][row] = xv.z; Xs[cq*4+3][row] = xv.w;
    Ys[cq*4+0][row] = yv.x; Ys[cq*4+1][row] = yv.y;
    Ys[cq*4+2][row] = yv.z; Ys[cq*4+3][row] = yv.w;
    __syncthreads();
#pragma unroll
    for (int kk = 0; kk < 16; ++kk) {
      float4 av = *(const float4*)(&Xs[kk][ty * 4]);
      float4 bv = *(const float4*)(&Ys[kk][tx * 4]);
      float ar[4] = {av.x, av.y, av.z, av.w};
      float br[4] = {bv.x, bv.y, bv.z, bv.w};
#pragma unroll
      for (int r = 0; r < 4; ++r)
#pragma unroll
        for (int c = 0; c < 4; ++c)
          acc[r][c] += ar[r] * br[c];
    }
  }
  float gv = fmaxf(fabsf(gamma[0]), 1e-4f);
  float ig2 = 1.4426950408889634f / gv;
  float rx[4], ry[4];
#pragma unroll
  for (int r = 0; r < 4; ++r) rx[r] = rnx[b * 256 + m0 + ty * 4 + r];
#pragma unroll
  for (int c = 0; c < 4; ++c) ry[c] = rny[b * 256 + n0 + tx * 4 + c];
  float* cbb = costR + (size_t)b * 65536;
  float* mbb = mR + (size_t)b * 65536;
#pragma unroll
  for (int r = 0; r < 4; ++r) {
    int m = m0 + ty * 4 + r;
    float c0 = (1.0f - acc[r][0] * rx[r] * ry[0]) * ig2;
    float c1 = (1.0f - acc[r][1] * rx[r] * ry[1]) * ig2;
    float c2 = (1.0f - acc[r][2] * rx[r] * ry[2]) * ig2;
    float c3 = (1.0f - acc[r][3] * rx[r] * ry[3]) * ig2;
    float4 stc = {c0, c1, c2, c3};
    float4 stm = {EXP2F(-c0), EXP2F(-c1), EXP2F(-c2), EXP2F(-c3)};
    *(float4*)(cbb + (size_t)m * 256 + n0 + tx * 4) = stc;
    *(float4*)(mbb + (size_t)m * 256 + n0 + tx * 4) = stm;
  }
}

// ---------------------------------------------------------------------------
// Kernel 3: forward soft-DTW in the P-DOMAIN.  One wave per batch (8 blocks
// x 64 -- R11 showed co-location on one CU serializes, never share a CU).
// Lane l owns columns 4l..4l+3, walks rows top->bottom, skewed (lane l does
// row r at slot s = r + l).  Representation: true p = 2^{-q} = P * 2^Q
// (P float, Q int per lane).  Recurrence:
//   P[r][c] = m[r][c] * (P_up + P_left + P_diag)  -- 2 adds + 1 mul chain,
// NO transcendentals on the chain.  Per-slot renorm: e = floor(log2 n3),
// P *= 2^-e, Q += e (pure VALU).  Cross-lane: shfl (P3, Q), ldexp adjust
// by (liQ - Q).  Recovery OFF-CHAIN: q = -Q - log2(P)  [R12 bug: sign of Q]
// stored row-major for the unchanged weights kernel.  Boundaries: p=0.
// ---------------------------------------------------------------------------
__global__ void __launch_bounds__(64, 1) fwd_kernel(const float* __restrict__ mR,
                                                    const float* __restrict__ gamma,
                                                    float* __restrict__ qR,
                                                    float* __restrict__ dist_out) {
  int b = blockIdx.x, l = threadIdx.x;
  float gv = fmaxf(fabsf(gamma[0]), 1e-4f);
  float gl = gv * 0.6931471805599453f;      // R = q * gl
  const float* mb = mR + (size_t)b * 65536 + 4 * l;
  float* qb = qR + (size_t)b * 65536 + 4 * l;
  float P0 = 0.f, P1 = 0.f, P2 = 0.f, P3 = 0.f;  // scaled p of row r-1
  int Q = 0;                                      // lane scale: p = P * 2^Q
  float ucar = (l == 0) ? 1.0f : 0.f;  // p(r-1, 4l-1); origin diag q=0 -> p=1
  float A0[4], A1[4], A2[4];
  auto loadC = [&](int s, float* buf) {
    int r = s - l; r = r < 0 ? 0 : (r > 255 ? 255 : r);
    ld4(buf, mb + (size_t)r * 256);
  };
  auto body = [&](int s, const float* mm) {
    int r = s - l;
    bool act = (unsigned)r <= 255u;
    float liP = __shfl_up(P3, 1);
    int   liQ = __shfl_up(Q, 1);
    float li = ldexpf(liP, liQ - Q);   // lane l-1's p(r, 4l-1) at my scale
    if (l == 0) li = 0.0f;
    float n0 = mm[0] * (P0 + li + ucar);
    float n1 = mm[1] * (P1 + n0 + P0);
    float n2 = mm[2] * (P2 + n1 + P1);
    float n3 = mm[3] * (P3 + n2 + P2);
    if (act) {
      float qf = -(float)Q;            // q = -Q - log2(n): off the chain
      float q3 = qf - LOG2F(n3);
      float4 st = {qf - LOG2F(n0), qf - LOG2F(n1), qf - LOG2F(n2), q3};
      *(float4*)(qb + (size_t)r * 256) = st;
      int e = (int)((__float_as_uint(n3) >> 23) & 255u) - 127;  // floor(log2 n3)
      P0 = ldexpf(n0, -e); P1 = ldexpf(n1, -e);
      P2 = ldexpf(n2, -e); P3 = ldexpf(n3, -e);
      ucar = ldexpf(li, -e);
      Q += e;
      if (l == 63 && r == 255) dist_out[b] = q3 * gl;
    }
  };
  loadC(0, A0); loadC(1, A1); loadC(2, A2);
  for (int it = 0; it < 107; ++it) {   // 321 slots; last live slot = 318
    int s = it * 3;
    body(s + 0, A0); loadC(s + 3, A0);
    body(s + 1, A1); loadC(s + 4, A1);
    body(s + 2, A2); loadC(s + 5, A2);
  }
}

// ---------------------------------------------------------------------------
// Kernel 3.5: backward weights, PACKED: record[(b*256+r)*64+l] = 16 floats
// (wd[0..3], wn[0..3], wr[0..3], pad) = one aligned 64 B line per (row,lane).
// Boundary masking folded in (w=0).  Reads/writes fully coalesced.
// ---------------------------------------------------------------------------
__global__ void __launch_bounds__(256) weights_kernel(const float* __restrict__ qR,
                                                      const float* __restrict__ costR,
                                                      float* __restrict__ W3) {
  int tid = blockIdx.x * 256 + threadIdx.x;   // = ((b*256 + r)*64 + l)
  int l = tid & 63;
  int r = (tid >> 6) & 255;
  int b = tid >> 14;
  const float* qb = qR + (size_t)b * 65536;
  const float* cbb = costR + (size_t)b * 65536;
  int rp = min(r + 1, 255);
  int c0i = 4 * l;
  int c4 = min(c0i + 4, 255);
  float q0a[5], q1a[5], c0a[5], c1a[5];
  ld4(q0a, qb + (size_t)r * 256 + c0i);  q0a[4] = qb[(size_t)r * 256 + c4];
  ld4(q1a, qb + (size_t)rp * 256 + c0i); q1a[4] = qb[(size_t)rp * 256 + c4];
  ld4(c0a, cbb + (size_t)r * 256 + c0i);  c0a[4] = cbb[(size_t)r * 256 + c4];
  ld4(c1a, cbb + (size_t)rp * 256 + c0i); c1a[4] = cbb[(size_t)rp * 256 + c4];
  const float CL = 50.0f * 1.4426950408889634f;
  bool rm = (r < 255);
  float w[16];
#pragma unroll
  for (int k = 0; k < 4; ++k) {
    bool cm = (c0i + k < 255);
    float ad = fminf(fmaxf((q1a[k+1] - c1a[k+1]) - q0a[k], -CL), CL);
    float an = fminf(fmaxf((q1a[k]   - c1a[k])   - q0a[k], -CL), CL);
    float ar = fminf(fmaxf((q0a[k+1] - c0a[k+1]) - q0a[k], -CL), CL);
    w[k]      = (rm && cm) ? EXP2F(ad) : 0.0f;
    w[4 + k]  = rm ? EXP2F(an) : 0.0f;
    w[8 + k]  = cm ? EXP2F(ar) : 0.0f;
    w[12 + k] = 0.0f;
  }
  float* wp = W3 + (size_t)tid * 16;
#pragma unroll
  for (int j = 0; j < 4; ++j) *(float4*)(wp + 4 * j) = *(float4*)(w + 4 * j);
}

// ---------------------------------------------------------------------------
// Kernel 4: backward recurrence, ROW-STRIP mirrored: lane l owns cols
// 4l..4l+3, walks rows bottom->top; lane l does row r at slot s = 318-r-l
// (lane 63 leads).  Per slot: ONE shfl_down, 12 FMAs, one 64 B packed-weight
// record via a 6-DEEP FIFO, one float4 E store DIRECTLY to d_out.
//   E[r][c] = E[r+1][c+1]*wd + E[r+1][c]*wn + E[r][c+1]*wr,  E[255][255]=1.
// ---------------------------------------------------------------------------
__global__ void __launch_bounds__(64, 1) bwd_kernel(const float* __restrict__ W3,
                                                    float* __restrict__ out) {
  int b = blockIdx.x, l = threadIdx.x;
  const float* wb = W3 + ((size_t)b * 16384 + l) * 16;   // + r*1024
  float* ob = out + (size_t)b * 65536 + 4 * l;
  float db0 = 0.f, db1 = 0.f, db2 = 0.f, db3 = 0.f;  // E[r+1][4l+k]
  float o0 = 0.f;       // my last row's col 4l value
  float dcar = 0.f;     // E[r+1][4l+4]
  float F0[16], F1[16], F2[16], F3[16], F4[16], F5[16];
  auto loadW = [&](int s, float* buf) {
    int r = 318 - s - l; r = r < 0 ? 0 : (r > 255 ? 255 : r);
    const float* p = wb + (size_t)r * 1024;
    ld4(buf, p); ld4(buf + 4, p + 4); ld4(buf + 8, p + 8); ld4(buf + 12, p + 12);
  };
  auto body = [&](int s, const float* w) {
    int r = 318 - s - l;
    bool act = (unsigned)r <= 255u;
    float ri = __shfl_down(o0, 1);   // E[r][4l+4] (lane l+1, one slot behind)
    if (l == 63) ri = 0.0f;
    float v3 = w[3] * dcar + w[7] * db3 + w[11] * ri;
    if (l == 63 && r == 255) v3 = 1.0f;     // seed E[255][255]
    float v2 = w[2] * db3 + w[6] * db2 + w[10] * v3;
    float v1 = w[1] * db2 + w[5] * db1 + w[9]  * v2;
    float v0 = w[0] * db1 + w[4] * db0 + w[8]  * v1;
    if (act) {
      float4 st = {v0, v1, v2, v3};
      *(float4*)(ob + (size_t)r * 256) = st;
      db0 = v0; db1 = v1; db2 = v2; db3 = v3;
      o0 = v0; dcar = ri;
    }
  };
  loadW(0, F0); loadW(1, F1); loadW(2, F2);
  loadW(3, F3); loadW(4, F4); loadW(5, F5);
  for (int it = 0; it < 54; ++it) {   // 324 slots; last live slot = 318
    int s = it * 6;
    body(s + 0, F0); loadW(s + 6,  F0);
    body(s + 1, F1); loadW(s + 7,  F1);
    body(s + 2, F2); loadW(s + 8,  F2);
    body(s + 3, F3); loadW(s + 9,  F3);
    body(s + 4, F4); loadW(s + 10, F4);
    body(s + 5, F5); loadW(s + 11, F5);
  }
}

// ---------------------------------------------------------------------------
// Workspace (floats), ~14.7 MB:
//   rnx @ 0 (2048) | rny @ 2048 (2048)
//   costR @ 4096   (8*65536, cost*ig2, row-major)
//   mR             (8*65536, exp2(-cost*ig2), row-major)
//   qR             (8*65536, row-major)
//   W3             (8*256*64*16 = 2,097,152: packed 64 B weight records)
// Alignment (E) goes straight into d_out from bwd_kernel.
// d_out: alignment [0 .. 524287], distance [524288 .. 524295].
// ---------------------------------------------------------------------------
extern "C" void kernel_launch(void* const* d_in, const int* in_sizes, int n_in,
                              void* d_out, int out_size, void* d_ws, size_t ws_size,
                              hipStream_t stream) {
  const float* x = (const float*)d_in[0];
  const float* y = (const float*)d_in[1];
  const float* gamma = (const float*)d_in[2];
  float* out = (float*)d_out;
  float* ws = (float*)d_ws;

  const size_t MAT = (size_t)8 * 65536;
  float* rnx   = ws;
  float* rny   = ws + 2048;
  float* costR = ws + 4096;
  float* mR    = costR + MAT;
  float* qR    = mR + MAT;
  float* W3    = qR + MAT;

  norms_kernel<<<1024, 256, 0, stream>>>(x, y, rnx, rny);
  cost_gemm<<<dim3(4, 4, 8), 256, 0, stream>>>(x, y, rnx, rny, gamma, costR, mR);
  fwd_kernel<<<8, 64, 0, stream>>>(mR, gamma, qR, out + 524288);
  weights_kernel<<<512, 256, 0, stream>>>(qR, costR, W3);
  bwd_kernel<<<8, 64, 0, stream>>>(W3, out);
}

// Round 14
// 190.469 us; speedup vs baseline: 2.1998x; 1.0859x over previous
//
#include <hip/hip_runtime.h>

// Problem constants: B=8, M=N=256, D=512
#define INFV 1.0e8f

// Raw HW transcendentals: v_exp_f32 is 2^x, v_log_f32 is log2(x).
#define EXP2F(x) __builtin_amdgcn_exp2f(x)
#define LOG2F(x) __builtin_amdgcn_logf(x)

__device__ __forceinline__ void ld4(float d[4], const float* p) {
  float4 v = *(const float4*)p;
  d[0] = v.x; d[1] = v.y; d[2] = v.z; d[3] = v.w;
}

// ---------------------------------------------------------------------------
// Kernel 1: inverse row norms.  rn = 1 / max(||row||, 1e-8)
// ---------------------------------------------------------------------------
__global__ void __launch_bounds__(256) norms_kernel(const float* __restrict__ x,
                                                    const float* __restrict__ y,
                                                    float* __restrict__ rnx,
                                                    float* __restrict__ rny) {
  int g = blockIdx.x * 4 + (threadIdx.x >> 6);
  int lane = threadIdx.x & 63;
  const float* src; float* dst; int row;
  if (g < 2048) { src = x; dst = rnx; row = g; }
  else          { src = y; dst = rny; row = g - 2048; }
  const float* p = src + (size_t)row * 512;
  float4 v0 = *(const float4*)(p + lane * 4);
  float4 v1 = *(const float4*)(p + 256 + lane * 4);
  float s = v0.x*v0.x + v0.y*v0.y + v0.z*v0.z + v0.w*v0.w
          + v1.x*v1.x + v1.y*v1.y + v1.z*v1.z + v1.w*v1.w;
#pragma unroll
  for (int o = 32; o > 0; o >>= 1) s += __shfl_xor(s, o, 64);
  if (lane == 0) dst[row] = 1.0f / fmaxf(sqrtf(s), 1e-8f);
}

// ---------------------------------------------------------------------------
// Kernel 2: cost GEMM -> ROW-MAJOR.  Two outputs, both scaled by ig2=log2e/gv:
//   costR = cost*ig2              (for the weights kernel)
//   mR    = exp2(-cost*ig2)       (for the p-domain forward kernel)
// ---------------------------------------------------------------------------
__global__ void __launch_bounds__(256) cost_gemm(const float* __restrict__ x,
                                                 const float* __restrict__ y,
                                                 const float* __restrict__ rnx,
                                                 const float* __restrict__ rny,
                                                 const float* __restrict__ gamma,
                                                 float* __restrict__ costR,
                                                 float* __restrict__ mR) {
  int b = blockIdx.z, mt = blockIdx.y, nt = blockIdx.x;
  int m0 = mt * 64, n0 = nt * 64;
  __shared__ float Xs[16][68];
  __shared__ float Ys[16][68];
  int tid = threadIdx.x;
  int row = tid >> 2, cq = tid & 3;
  int tx = tid & 15, ty = tid >> 4;
  const float* xb = x + ((size_t)b * 256 + m0) * 512;
  const float* yb = y + ((size_t)b * 256 + n0) * 512;
  float acc[4][4] = {};
  for (int k0 = 0; k0 < 512; k0 += 16) {
    float4 xv = *(const float4*)(xb + (size_t)row * 512 + k0 + cq * 4);
    float4 yv = *(const float4*)(yb + (size_t)row * 512 + k0 + cq * 4);
    __syncthreads();
    Xs[cq*4+0][row] = xv.x; Xs[cq*4+1][row] = xv.y;
    Xs[cq*4+2][row] = xv.z; Xs[cq*4+3][row] = xv.w;
    Ys[cq*4+0][row] = yv.x; Ys[cq*4+1][row] = yv.y;
    Ys[cq*4+2][row] = yv.z; Ys[cq*4+3][row] = yv.w;
    __syncthreads();
#pragma unroll
    for (int kk = 0; kk < 16; ++kk) {
      float4 av = *(const float4*)(&Xs[kk][ty * 4]);
      float4 bv = *(const float4*)(&Ys[kk][tx * 4]);
      float ar[4] = {av.x, av.y, av.z, av.w};
      float br[4] = {bv.x, bv.y, bv.z, bv.w};
#pragma unroll
      for (int r = 0; r < 4; ++r)
#pragma unroll
        for (int c = 0; c < 4; ++c)
          acc[r][c] += ar[r] * br[c];
    }
  }
  float gv = fmaxf(fabsf(gamma[0]), 1e-4f);
  float ig2 = 1.4426950408889634f / gv;
  float rx[4], ry[4];
#pragma unroll
  for (int r = 0; r < 4; ++r) rx[r] = rnx[b * 256 + m0 + ty * 4 + r];
#pragma unroll
  for (int c = 0; c < 4; ++c) ry[c] = rny[b * 256 + n0 + tx * 4 + c];
  float* cbb = costR + (size_t)b * 65536;
  float* mbb = mR + (size_t)b * 65536;
#pragma unroll
  for (int r = 0; r < 4; ++r) {
    int m = m0 + ty * 4 + r;
    float c0 = (1.0f - acc[r][0] * rx[r] * ry[0]) * ig2;
    float c1 = (1.0f - acc[r][1] * rx[r] * ry[1]) * ig2;
    float c2 = (1.0f - acc[r][2] * rx[r] * ry[2]) * ig2;
    float c3 = (1.0f - acc[r][3] * rx[r] * ry[3]) * ig2;
    float4 stc = {c0, c1, c2, c3};
    float4 stm = {EXP2F(-c0), EXP2F(-c1), EXP2F(-c2), EXP2F(-c3)};
    *(float4*)(cbb + (size_t)m * 256 + n0 + tx * 4) = stc;
    *(float4*)(mbb + (size_t)m * 256 + n0 + tx * 4) = stm;
  }
}

// ---------------------------------------------------------------------------
// Kernel 3: forward soft-DTW in the P-DOMAIN.  One wave per batch (8 blocks
// x 64 -- R11: never share a CU).  Lane l owns columns 4l..4l+3, walks rows
// top->bottom, skewed (lane l does row r at slot s = r + l).  p = P * 2^Q.
//   P[r][c] = m[r][c] * (P_up + P_left + P_diag)  -- no transcendentals on
// the chain; renorm via exponent extract + v_ldexp; q = -Q - log2(P)
// recovered off-chain.  Cost FIFO depth 8 (R13: slot time was latency/depth
// at depth 3 -> ~480 cyc; depth 8 targets ~200).
// ---------------------------------------------------------------------------
__global__ void __launch_bounds__(64, 1) fwd_kernel(const float* __restrict__ mR,
                                                    const float* __restrict__ gamma,
                                                    float* __restrict__ qR,
                                                    float* __restrict__ dist_out) {
  int b = blockIdx.x, l = threadIdx.x;
  float gv = fmaxf(fabsf(gamma[0]), 1e-4f);
  float gl = gv * 0.6931471805599453f;      // R = q * gl
  const float* mb = mR + (size_t)b * 65536 + 4 * l;
  float* qb = qR + (size_t)b * 65536 + 4 * l;
  float P0 = 0.f, P1 = 0.f, P2 = 0.f, P3 = 0.f;  // scaled p of row r-1
  int Q = 0;                                      // lane scale: p = P * 2^Q
  float ucar = (l == 0) ? 1.0f : 0.f;  // p(r-1, 4l-1); origin diag q=0 -> p=1
  float A0[4], A1[4], A2[4], A3[4], A4[4], A5[4], A6[4], A7[4];
  auto loadC = [&](int s, float* buf) {
    int r = s - l; r = r < 0 ? 0 : (r > 255 ? 255 : r);
    ld4(buf, mb + (size_t)r * 256);
  };
  auto body = [&](int s, const float* mm) {
    int r = s - l;
    bool act = (unsigned)r <= 255u;
    float liP = __shfl_up(P3, 1);
    int   liQ = __shfl_up(Q, 1);
    float li = ldexpf(liP, liQ - Q);   // lane l-1's p(r, 4l-1) at my scale
    if (l == 0) li = 0.0f;
    float n0 = mm[0] * (P0 + li + ucar);
    float n1 = mm[1] * (P1 + n0 + P0);
    float n2 = mm[2] * (P2 + n1 + P1);
    float n3 = mm[3] * (P3 + n2 + P2);
    if (act) {
      float qf = -(float)Q;            // q = -Q - log2(n): off the chain
      float q3 = qf - LOG2F(n3);
      float4 st = {qf - LOG2F(n0), qf - LOG2F(n1), qf - LOG2F(n2), q3};
      *(float4*)(qb + (size_t)r * 256) = st;
      int e = (int)((__float_as_uint(n3) >> 23) & 255u) - 127;  // floor(log2 n3)
      P0 = ldexpf(n0, -e); P1 = ldexpf(n1, -e);
      P2 = ldexpf(n2, -e); P3 = ldexpf(n3, -e);
      ucar = ldexpf(li, -e);
      Q += e;
      if (l == 63 && r == 255) dist_out[b] = q3 * gl;
    }
  };
  loadC(0, A0); loadC(1, A1); loadC(2, A2); loadC(3, A3);
  loadC(4, A4); loadC(5, A5); loadC(6, A6); loadC(7, A7);
  for (int it = 0; it < 41; ++it) {   // 328 slots; last live slot = 318
    int s = it * 8;
    body(s + 0, A0); loadC(s + 8,  A0);
    body(s + 1, A1); loadC(s + 9,  A1);
    body(s + 2, A2); loadC(s + 10, A2);
    body(s + 3, A3); loadC(s + 11, A3);
    body(s + 4, A4); loadC(s + 12, A4);
    body(s + 5, A5); loadC(s + 13, A5);
    body(s + 6, A6); loadC(s + 14, A6);
    body(s + 7, A7); loadC(s + 15, A7);
  }
}

// ---------------------------------------------------------------------------
// Kernel 3.5: backward weights, PACKED: record[(b*256+r)*64+l] = 16 floats
// (wd[0..3], wn[0..3], wr[0..3], pad) = one aligned 64 B line per (row,lane).
// Boundary masking folded in (w=0).  Reads/writes fully coalesced.
// ---------------------------------------------------------------------------
__global__ void __launch_bounds__(256) weights_kernel(const float* __restrict__ qR,
                                                      const float* __restrict__ costR,
                                                      float* __restrict__ W3) {
  int tid = blockIdx.x * 256 + threadIdx.x;   // = ((b*256 + r)*64 + l)
  int l = tid & 63;
  int r = (tid >> 6) & 255;
  int b = tid >> 14;
  const float* qb = qR + (size_t)b * 65536;
  const float* cbb = costR + (size_t)b * 65536;
  int rp = min(r + 1, 255);
  int c0i = 4 * l;
  int c4 = min(c0i + 4, 255);
  float q0a[5], q1a[5], c0a[5], c1a[5];
  ld4(q0a, qb + (size_t)r * 256 + c0i);  q0a[4] = qb[(size_t)r * 256 + c4];
  ld4(q1a, qb + (size_t)rp * 256 + c0i); q1a[4] = qb[(size_t)rp * 256 + c4];
  ld4(c0a, cbb + (size_t)r * 256 + c0i);  c0a[4] = cbb[(size_t)r * 256 + c4];
  ld4(c1a, cbb + (size_t)rp * 256 + c0i); c1a[4] = cbb[(size_t)rp * 256 + c4];
  const float CL = 50.0f * 1.4426950408889634f;
  bool rm = (r < 255);
  float w[16];
#pragma unroll
  for (int k = 0; k < 4; ++k) {
    bool cm = (c0i + k < 255);
    float ad = fminf(fmaxf((q1a[k+1] - c1a[k+1]) - q0a[k], -CL), CL);
    float an = fminf(fmaxf((q1a[k]   - c1a[k])   - q0a[k], -CL), CL);
    float ar = fminf(fmaxf((q0a[k+1] - c0a[k+1]) - q0a[k], -CL), CL);
    w[k]      = (rm && cm) ? EXP2F(ad) : 0.0f;
    w[4 + k]  = rm ? EXP2F(an) : 0.0f;
    w[8 + k]  = cm ? EXP2F(ar) : 0.0f;
    w[12 + k] = 0.0f;
  }
  float* wp = W3 + (size_t)tid * 16;
#pragma unroll
  for (int j = 0; j < 4; ++j) *(float4*)(wp + 4 * j) = *(float4*)(w + 4 * j);
}

// ---------------------------------------------------------------------------
// Kernel 4: backward recurrence, ROW-STRIP mirrored: lane l owns cols
// 4l..4l+3, walks rows bottom->top; lane l does row r at slot s = 318-r-l
// (lane 63 leads).  Per slot: ONE shfl_down, 12 FMAs, one 64 B packed-weight
// record via an 8-DEEP FIFO, one float4 E store DIRECTLY to d_out.
//   E[r][c] = E[r+1][c+1]*wd + E[r+1][c]*wn + E[r][c+1]*wr,  E[255][255]=1.
// ---------------------------------------------------------------------------
__global__ void __launch_bounds__(64, 1) bwd_kernel(const float* __restrict__ W3,
                                                    float* __restrict__ out) {
  int b = blockIdx.x, l = threadIdx.x;
  const float* wb = W3 + ((size_t)b * 16384 + l) * 16;   // + r*1024
  float* ob = out + (size_t)b * 65536 + 4 * l;
  float db0 = 0.f, db1 = 0.f, db2 = 0.f, db3 = 0.f;  // E[r+1][4l+k]
  float o0 = 0.f;       // my last row's col 4l value
  float dcar = 0.f;     // E[r+1][4l+4]
  float F0[16], F1[16], F2[16], F3[16], F4[16], F5[16], F6[16], F7[16];
  auto loadW = [&](int s, float* buf) {
    int r = 318 - s - l; r = r < 0 ? 0 : (r > 255 ? 255 : r);
    const float* p = wb + (size_t)r * 1024;
    ld4(buf, p); ld4(buf + 4, p + 4); ld4(buf + 8, p + 8); ld4(buf + 12, p + 12);
  };
  auto body = [&](int s, const float* w) {
    int r = 318 - s - l;
    bool act = (unsigned)r <= 255u;
    float ri = __shfl_down(o0, 1);   // E[r][4l+4] (lane l+1, one slot behind)
    if (l == 63) ri = 0.0f;
    float v3 = w[3] * dcar + w[7] * db3 + w[11] * ri;
    if (l == 63 && r == 255) v3 = 1.0f;     // seed E[255][255]
    float v2 = w[2] * db3 + w[6] * db2 + w[10] * v3;
    float v1 = w[1] * db2 + w[5] * db1 + w[9]  * v2;
    float v0 = w[0] * db1 + w[4] * db0 + w[8]  * v1;
    if (act) {
      float4 st = {v0, v1, v2, v3};
      *(float4*)(ob + (size_t)r * 256) = st;
      db0 = v0; db1 = v1; db2 = v2; db3 = v3;
      o0 = v0; dcar = ri;
    }
  };
  loadW(0, F0); loadW(1, F1); loadW(2, F2); loadW(3, F3);
  loadW(4, F4); loadW(5, F5); loadW(6, F6); loadW(7, F7);
  for (int it = 0; it < 41; ++it) {   // 328 slots; last live slot = 318
    int s = it * 8;
    body(s + 0, F0); loadW(s + 8,  F0);
    body(s + 1, F1); loadW(s + 9,  F1);
    body(s + 2, F2); loadW(s + 10, F2);
    body(s + 3, F3); loadW(s + 11, F3);
    body(s + 4, F4); loadW(s + 12, F4);
    body(s + 5, F5); loadW(s + 13, F5);
    body(s + 6, F6); loadW(s + 14, F6);
    body(s + 7, F7); loadW(s + 15, F7);
  }
}

// ---------------------------------------------------------------------------
// Workspace (floats), ~14.7 MB:
//   rnx @ 0 (2048) | rny @ 2048 (2048)
//   costR @ 4096   (8*65536, cost*ig2, row-major)
//   mR             (8*65536, exp2(-cost*ig2), row-major)
//   qR             (8*65536, row-major)
//   W3             (8*256*64*16 = 2,097,152: packed 64 B weight records)
// Alignment (E) goes straight into d_out from bwd_kernel.
// d_out: alignment [0 .. 524287], distance [524288 .. 524295].
// ---------------------------------------------------------------------------
extern "C" void kernel_launch(void* const* d_in, const int* in_sizes, int n_in,
                              void* d_out, int out_size, void* d_ws, size_t ws_size,
                              hipStream_t stream) {
  const float* x = (const float*)d_in[0];
  const float* y = (const float*)d_in[1];
  const float* gamma = (const float*)d_in[2];
  float* out = (float*)d_out;
  float* ws = (float*)d_ws;

  const size_t MAT = (size_t)8 * 65536;
  float* rnx   = ws;
  float* rny   = ws + 2048;
  float* costR = ws + 4096;
  float* mR    = costR + MAT;
  float* qR    = mR + MAT;
  float* W3    = qR + MAT;

  norms_kernel<<<1024, 256, 0, stream>>>(x, y, rnx, rny);
  cost_gemm<<<dim3(4, 4, 8), 256, 0, stream>>>(x, y, rnx, rny, gamma, costR, mR);
  fwd_kernel<<<8, 64, 0, stream>>>(mR, gamma, qR, out + 524288);
  weights_kernel<<<512, 256, 0, stream>>>(qR, costR, W3);
  bwd_kernel<<<8, 64, 0, stream>>>(W3, out);
}

// Round 15
// 187.759 us; speedup vs baseline: 2.2315x; 1.0144x over previous
//
#include <hip/hip_runtime.h>

// Problem constants: B=8, M=N=256, D=512
#define INFV 1.0e8f

// Raw HW transcendentals: v_exp_f32 is 2^x, v_log_f32 is log2(x).
#define EXP2F(x) __builtin_amdgcn_exp2f(x)
#define LOG2F(x) __builtin_amdgcn_logf(x)

__device__ __forceinline__ void ld4(float d[4], const float* p) {
  float4 v = *(const float4*)p;
  d[0] = v.x; d[1] = v.y; d[2] = v.z; d[3] = v.w;
}

// ---------------------------------------------------------------------------
// Kernel 1: inverse row norms.  rn = 1 / max(||row||, 1e-8)
// ---------------------------------------------------------------------------
__global__ void __launch_bounds__(256) norms_kernel(const float* __restrict__ x,
                                                    const float* __restrict__ y,
                                                    float* __restrict__ rnx,
                                                    float* __restrict__ rny) {
  int g = blockIdx.x * 4 + (threadIdx.x >> 6);
  int lane = threadIdx.x & 63;
  const float* src; float* dst; int row;
  if (g < 2048) { src = x; dst = rnx; row = g; }
  else          { src = y; dst = rny; row = g - 2048; }
  const float* p = src + (size_t)row * 512;
  float4 v0 = *(const float4*)(p + lane * 4);
  float4 v1 = *(const float4*)(p + 256 + lane * 4);
  float s = v0.x*v0.x + v0.y*v0.y + v0.z*v0.z + v0.w*v0.w
          + v1.x*v1.x + v1.y*v1.y + v1.z*v1.z + v1.w*v1.w;
#pragma unroll
  for (int o = 32; o > 0; o >>= 1) s += __shfl_xor(s, o, 64);
  if (lane == 0) dst[row] = 1.0f / fmaxf(sqrtf(s), 1e-8f);
}

// ---------------------------------------------------------------------------
// Kernel 2: cost GEMM -> ROW-MAJOR, 32x64 tiles (256 blocks: fills all CUs,
// half the per-block serial FMA work of the old 64x64).  Two outputs, both
// scaled by ig2=log2e/gv:
//   costR = cost*ig2              (for the weights kernel)
//   mR    = exp2(-cost*ig2)       (for the p-domain forward kernel)
// ---------------------------------------------------------------------------
__global__ void __launch_bounds__(256) cost_gemm(const float* __restrict__ x,
                                                 const float* __restrict__ y,
                                                 const float* __restrict__ rnx,
                                                 const float* __restrict__ rny,
                                                 const float* __restrict__ gamma,
                                                 float* __restrict__ costR,
                                                 float* __restrict__ mR) {
  int b = blockIdx.z, mt = blockIdx.y, nt = blockIdx.x;
  int m0 = mt * 32, n0 = nt * 64;
  __shared__ float Xs[16][36];
  __shared__ float Ys[16][68];
  int tid = threadIdx.x;
  int row = tid >> 2, cq = tid & 3;      // staging indices
  int tx = tid & 15, ty = tid >> 4;      // compute: 16x16 grid, 2x4 micro-tile
  const float* xb = x + ((size_t)b * 256 + m0) * 512;
  const float* yb = y + ((size_t)b * 256 + n0) * 512;
  float acc[2][4] = {};
  for (int k0 = 0; k0 < 512; k0 += 16) {
    float4 xv;
    if (tid < 128) xv = *(const float4*)(xb + (size_t)row * 512 + k0 + cq * 4);
    float4 yv = *(const float4*)(yb + (size_t)row * 512 + k0 + cq * 4);
    __syncthreads();
    if (tid < 128) {
      Xs[cq*4+0][row] = xv.x; Xs[cq*4+1][row] = xv.y;
      Xs[cq*4+2][row] = xv.z; Xs[cq*4+3][row] = xv.w;
    }
    Ys[cq*4+0][row] = yv.x; Ys[cq*4+1][row] = yv.y;
    Ys[cq*4+2][row] = yv.z; Ys[cq*4+3][row] = yv.w;
    __syncthreads();
#pragma unroll
    for (int kk = 0; kk < 16; ++kk) {
      float a0 = Xs[kk][ty * 2 + 0];
      float a1 = Xs[kk][ty * 2 + 1];
      float4 bv = *(const float4*)(&Ys[kk][tx * 4]);
      float br[4] = {bv.x, bv.y, bv.z, bv.w};
#pragma unroll
      for (int c = 0; c < 4; ++c) {
        acc[0][c] += a0 * br[c];
        acc[1][c] += a1 * br[c];
      }
    }
  }
  float gv = fmaxf(fabsf(gamma[0]), 1e-4f);
  float ig2 = 1.4426950408889634f / gv;
  float rx[2], ry[4];
#pragma unroll
  for (int r = 0; r < 2; ++r) rx[r] = rnx[b * 256 + m0 + ty * 2 + r];
#pragma unroll
  for (int c = 0; c < 4; ++c) ry[c] = rny[b * 256 + n0 + tx * 4 + c];
  float* cbb = costR + (size_t)b * 65536;
  float* mbb = mR + (size_t)b * 65536;
#pragma unroll
  for (int r = 0; r < 2; ++r) {
    int m = m0 + ty * 2 + r;
    float c0 = (1.0f - acc[r][0] * rx[r] * ry[0]) * ig2;
    float c1 = (1.0f - acc[r][1] * rx[r] * ry[1]) * ig2;
    float c2 = (1.0f - acc[r][2] * rx[r] * ry[2]) * ig2;
    float c3 = (1.0f - acc[r][3] * rx[r] * ry[3]) * ig2;
    float4 stc = {c0, c1, c2, c3};
    float4 stm = {EXP2F(-c0), EXP2F(-c1), EXP2F(-c2), EXP2F(-c3)};
    *(float4*)(cbb + (size_t)m * 256 + n0 + tx * 4) = stc;
    *(float4*)(mbb + (size_t)m * 256 + n0 + tx * 4) = stm;
  }
}

// ---------------------------------------------------------------------------
// Kernel 3: forward soft-DTW in the P-DOMAIN.  One wave per batch (8 blocks
// x 64 -- R11: never share a CU).  Lane l owns columns 4l..4l+3, walks rows
// top->bottom, skewed (lane l does row r at slot s = r + l).  p = P * 2^Q.
//   P[r][c] = m[r][c] * (P_up + P_left + P_diag)  -- no transcendentals on
// the chain; renorm via exponent extract + v_ldexp; q = -Q - log2(P)
// recovered off-chain.  Cost FIFO depth 16 (R14: depth 3->8 gave 484->350
// cyc/slot; still concurrency-limited, deepen further).
// ---------------------------------------------------------------------------
__global__ void __launch_bounds__(64, 1) fwd_kernel(const float* __restrict__ mR,
                                                    const float* __restrict__ gamma,
                                                    float* __restrict__ qR,
                                                    float* __restrict__ dist_out) {
  int b = blockIdx.x, l = threadIdx.x;
  float gv = fmaxf(fabsf(gamma[0]), 1e-4f);
  float gl = gv * 0.6931471805599453f;      // R = q * gl
  const float* mb = mR + (size_t)b * 65536 + 4 * l;
  float* qb = qR + (size_t)b * 65536 + 4 * l;
  float P0 = 0.f, P1 = 0.f, P2 = 0.f, P3 = 0.f;  // scaled p of row r-1
  int Q = 0;                                      // lane scale: p = P * 2^Q
  float ucar = (l == 0) ? 1.0f : 0.f;  // p(r-1, 4l-1); origin diag q=0 -> p=1
  float A0[4], A1[4], A2[4], A3[4], A4[4], A5[4], A6[4], A7[4];
  float A8[4], A9[4], A10[4], A11[4], A12[4], A13[4], A14[4], A15[4];
  auto loadC = [&](int s, float* buf) {
    int r = s - l; r = r < 0 ? 0 : (r > 255 ? 255 : r);
    ld4(buf, mb + (size_t)r * 256);
  };
  auto body = [&](int s, const float* mm) {
    int r = s - l;
    bool act = (unsigned)r <= 255u;
    float liP = __shfl_up(P3, 1);
    int   liQ = __shfl_up(Q, 1);
    float li = ldexpf(liP, liQ - Q);   // lane l-1's p(r, 4l-1) at my scale
    if (l == 0) li = 0.0f;
    float n0 = mm[0] * (P0 + li + ucar);
    float n1 = mm[1] * (P1 + n0 + P0);
    float n2 = mm[2] * (P2 + n1 + P1);
    float n3 = mm[3] * (P3 + n2 + P2);
    if (act) {
      float qf = -(float)Q;            // q = -Q - log2(n): off the chain
      float q3 = qf - LOG2F(n3);
      float4 st = {qf - LOG2F(n0), qf - LOG2F(n1), qf - LOG2F(n2), q3};
      *(float4*)(qb + (size_t)r * 256) = st;
      int e = (int)((__float_as_uint(n3) >> 23) & 255u) - 127;  // floor(log2 n3)
      P0 = ldexpf(n0, -e); P1 = ldexpf(n1, -e);
      P2 = ldexpf(n2, -e); P3 = ldexpf(n3, -e);
      ucar = ldexpf(li, -e);
      Q += e;
      if (l == 63 && r == 255) dist_out[b] = q3 * gl;
    }
  };
  loadC(0, A0);  loadC(1, A1);  loadC(2, A2);  loadC(3, A3);
  loadC(4, A4);  loadC(5, A5);  loadC(6, A6);  loadC(7, A7);
  loadC(8, A8);  loadC(9, A9);  loadC(10, A10); loadC(11, A11);
  loadC(12, A12); loadC(13, A13); loadC(14, A14); loadC(15, A15);
  for (int it = 0; it < 21; ++it) {   // 336 slots; last live slot = 318
    int s = it * 16;
    body(s + 0,  A0);  loadC(s + 16, A0);
    body(s + 1,  A1);  loadC(s + 17, A1);
    body(s + 2,  A2);  loadC(s + 18, A2);
    body(s + 3,  A3);  loadC(s + 19, A3);
    body(s + 4,  A4);  loadC(s + 20, A4);
    body(s + 5,  A5);  loadC(s + 21, A5);
    body(s + 6,  A6);  loadC(s + 22, A6);
    body(s + 7,  A7);  loadC(s + 23, A7);
    body(s + 8,  A8);  loadC(s + 24, A8);
    body(s + 9,  A9);  loadC(s + 25, A9);
    body(s + 10, A10); loadC(s + 26, A10);
    body(s + 11, A11); loadC(s + 27, A11);
    body(s + 12, A12); loadC(s + 28, A12);
    body(s + 13, A13); loadC(s + 29, A13);
    body(s + 14, A14); loadC(s + 30, A14);
    body(s + 15, A15); loadC(s + 31, A15);
  }
}

// ---------------------------------------------------------------------------
// Kernel 3.5: backward weights, PACKED: record[(b*256+r)*64+l] = 16 floats
// (wd[0..3], wn[0..3], wr[0..3], pad) = one aligned 64 B line per (row,lane).
// Boundary masking folded in (w=0).  Reads/writes fully coalesced.
// ---------------------------------------------------------------------------
__global__ void __launch_bounds__(256) weights_kernel(const float* __restrict__ qR,
                                                      const float* __restrict__ costR,
                                                      float* __restrict__ W3) {
  int tid = blockIdx.x * 256 + threadIdx.x;   // = ((b*256 + r)*64 + l)
  int l = tid & 63;
  int r = (tid >> 6) & 255;
  int b = tid >> 14;
  const float* qb = qR + (size_t)b * 65536;
  const float* cbb = costR + (size_t)b * 65536;
  int rp = min(r + 1, 255);
  int c0i = 4 * l;
  int c4 = min(c0i + 4, 255);
  float q0a[5], q1a[5], c0a[5], c1a[5];
  ld4(q0a, qb + (size_t)r * 256 + c0i);  q0a[4] = qb[(size_t)r * 256 + c4];
  ld4(q1a, qb + (size_t)rp * 256 + c0i); q1a[4] = qb[(size_t)rp * 256 + c4];
  ld4(c0a, cbb + (size_t)r * 256 + c0i);  c0a[4] = cbb[(size_t)r * 256 + c4];
  ld4(c1a, cbb + (size_t)rp * 256 + c0i); c1a[4] = cbb[(size_t)rp * 256 + c4];
  const float CL = 50.0f * 1.4426950408889634f;
  bool rm = (r < 255);
  float w[16];
#pragma unroll
  for (int k = 0; k < 4; ++k) {
    bool cm = (c0i + k < 255);
    float ad = fminf(fmaxf((q1a[k+1] - c1a[k+1]) - q0a[k], -CL), CL);
    float an = fminf(fmaxf((q1a[k]   - c1a[k])   - q0a[k], -CL), CL);
    float ar = fminf(fmaxf((q0a[k+1] - c0a[k+1]) - q0a[k], -CL), CL);
    w[k]      = (rm && cm) ? EXP2F(ad) : 0.0f;
    w[4 + k]  = rm ? EXP2F(an) : 0.0f;
    w[8 + k]  = cm ? EXP2F(ar) : 0.0f;
    w[12 + k] = 0.0f;
  }
  float* wp = W3 + (size_t)tid * 16;
#pragma unroll
  for (int j = 0; j < 4; ++j) *(float4*)(wp + 4 * j) = *(float4*)(w + 4 * j);
}

// ---------------------------------------------------------------------------
// Kernel 4: backward recurrence, ROW-STRIP mirrored: lane l owns cols
// 4l..4l+3, walks rows bottom->top; lane l does row r at slot s = 318-r-l
// (lane 63 leads).  Per slot: ONE shfl_down, 12 FMAs, one 64 B packed-weight
// record via a 12-DEEP FIFO, one float4 E store DIRECTLY to d_out.
//   E[r][c] = E[r+1][c+1]*wd + E[r+1][c]*wn + E[r][c+1]*wr,  E[255][255]=1.
// ---------------------------------------------------------------------------
__global__ void __launch_bounds__(64, 1) bwd_kernel(const float* __restrict__ W3,
                                                    float* __restrict__ out) {
  int b = blockIdx.x, l = threadIdx.x;
  const float* wb = W3 + ((size_t)b * 16384 + l) * 16;   // + r*1024
  float* ob = out + (size_t)b * 65536 + 4 * l;
  float db0 = 0.f, db1 = 0.f, db2 = 0.f, db3 = 0.f;  // E[r+1][4l+k]
  float o0 = 0.f;       // my last row's col 4l value
  float dcar = 0.f;     // E[r+1][4l+4]
  float F0[16], F1[16], F2[16], F3[16], F4[16], F5[16];
  float F6[16], F7[16], F8[16], F9[16], F10[16], F11[16];
  auto loadW = [&](int s, float* buf) {
    int r = 318 - s - l; r = r < 0 ? 0 : (r > 255 ? 255 : r);
    const float* p = wb + (size_t)r * 1024;
    ld4(buf, p); ld4(buf + 4, p + 4); ld4(buf + 8, p + 8); ld4(buf + 12, p + 12);
  };
  auto body = [&](int s, const float* w) {
    int r = 318 - s - l;
    bool act = (unsigned)r <= 255u;
    float ri = __shfl_down(o0, 1);   // E[r][4l+4] (lane l+1, one slot behind)
    if (l == 63) ri = 0.0f;
    float v3 = w[3] * dcar + w[7] * db3 + w[11] * ri;
    if (l == 63 && r == 255) v3 = 1.0f;     // seed E[255][255]
    float v2 = w[2] * db3 + w[6] * db2 + w[10] * v3;
    float v1 = w[1] * db2 + w[5] * db1 + w[9]  * v2;
    float v0 = w[0] * db1 + w[4] * db0 + w[8]  * v1;
    if (act) {
      float4 st = {v0, v1, v2, v3};
      *(float4*)(ob + (size_t)r * 256) = st;
      db0 = v0; db1 = v1; db2 = v2; db3 = v3;
      o0 = v0; dcar = ri;
    }
  };
  loadW(0, F0); loadW(1, F1); loadW(2, F2); loadW(3, F3);
  loadW(4, F4); loadW(5, F5); loadW(6, F6); loadW(7, F7);
  loadW(8, F8); loadW(9, F9); loadW(10, F10); loadW(11, F11);
  for (int it = 0; it < 28; ++it) {   // 336 slots; last live slot = 318
    int s = it * 12;
    body(s + 0,  F0);  loadW(s + 12, F0);
    body(s + 1,  F1);  loadW(s + 13, F1);
    body(s + 2,  F2);  loadW(s + 14, F2);
    body(s + 3,  F3);  loadW(s + 15, F3);
    body(s + 4,  F4);  loadW(s + 16, F4);
    body(s + 5,  F5);  loadW(s + 17, F5);
    body(s + 6,  F6);  loadW(s + 18, F6);
    body(s + 7,  F7);  loadW(s + 19, F7);
    body(s + 8,  F8);  loadW(s + 20, F8);
    body(s + 9,  F9);  loadW(s + 21, F9);
    body(s + 10, F10); loadW(s + 22, F10);
    body(s + 11, F11); loadW(s + 23, F11);
  }
}

// ---------------------------------------------------------------------------
// Workspace (floats), ~14.7 MB:
//   rnx @ 0 (2048) | rny @ 2048 (2048)
//   costR @ 4096   (8*65536, cost*ig2, row-major)
//   mR             (8*65536, exp2(-cost*ig2), row-major)
//   qR             (8*65536, row-major)
//   W3             (8*256*64*16 = 2,097,152: packed 64 B weight records)
// Alignment (E) goes straight into d_out from bwd_kernel.
// d_out: alignment [0 .. 524287], distance [524288 .. 524295].
// ---------------------------------------------------------------------------
extern "C" void kernel_launch(void* const* d_in, const int* in_sizes, int n_in,
                              void* d_out, int out_size, void* d_ws, size_t ws_size,
                              hipStream_t stream) {
  const float* x = (const float*)d_in[0];
  const float* y = (const float*)d_in[1];
  const float* gamma = (const float*)d_in[2];
  float* out = (float*)d_out;
  float* ws = (float*)d_ws;

  const size_t MAT = (size_t)8 * 65536;
  float* rnx   = ws;
  float* rny   = ws + 2048;
  float* costR = ws + 4096;
  float* mR    = costR + MAT;
  float* qR    = mR + MAT;
  float* W3    = qR + MAT;

  norms_kernel<<<1024, 256, 0, stream>>>(x, y, rnx, rny);
  cost_gemm<<<dim3(4, 8, 8), 256, 0, stream>>>(x, y, rnx, rny, gamma, costR, mR);
  fwd_kernel<<<8, 64, 0, stream>>>(mR, gamma, qR, out + 524288);
  weights_kernel<<<512, 256, 0, stream>>>(qR, costR, W3);
  bwd_kernel<<<8, 64, 0, stream>>>(W3, out);
}

// Round 16
// 179.432 us; speedup vs baseline: 2.3351x; 1.0464x over previous
//
#include <hip/hip_runtime.h>

// Problem constants: B=8, M=N=256, D=512
#define INFV 1.0e8f

// Raw HW transcendentals: v_exp_f32 is 2^x, v_log_f32 is log2(x).
#define EXP2F(x) __builtin_amdgcn_exp2f(x)
#define LOG2F(x) __builtin_amdgcn_logf(x)

__device__ __forceinline__ void ld4(float d[4], const float* p) {
  float4 v = *(const float4*)p;
  d[0] = v.x; d[1] = v.y; d[2] = v.z; d[3] = v.w;
}

// ---------------------------------------------------------------------------
// Kernel 1: inverse row norms.  rn = 1 / max(||row||, 1e-8)
// ---------------------------------------------------------------------------
__global__ void __launch_bounds__(256) norms_kernel(const float* __restrict__ x,
                                                    const float* __restrict__ y,
                                                    float* __restrict__ rnx,
                                                    float* __restrict__ rny) {
  int g = blockIdx.x * 4 + (threadIdx.x >> 6);
  int lane = threadIdx.x & 63;
  const float* src; float* dst; int row;
  if (g < 2048) { src = x; dst = rnx; row = g; }
  else          { src = y; dst = rny; row = g - 2048; }
  const float* p = src + (size_t)row * 512;
  float4 v0 = *(const float4*)(p + lane * 4);
  float4 v1 = *(const float4*)(p + 256 + lane * 4);
  float s = v0.x*v0.x + v0.y*v0.y + v0.z*v0.z + v0.w*v0.w
          + v1.x*v1.x + v1.y*v1.y + v1.z*v1.z + v1.w*v1.w;
#pragma unroll
  for (int o = 32; o > 0; o >>= 1) s += __shfl_xor(s, o, 64);
  if (lane == 0) dst[row] = 1.0f / fmaxf(sqrtf(s), 1e-8f);
}

// ---------------------------------------------------------------------------
// Kernel 2: cost GEMM -> ROW-MAJOR, 32x64 tiles (256 blocks).  Two outputs,
// both scaled by ig2=log2e/gv:
//   costR = cost*ig2              (for the weights kernel)
//   mR    = exp2(-cost*ig2)       (for the p-domain forward kernel)
// ---------------------------------------------------------------------------
__global__ void __launch_bounds__(256) cost_gemm(const float* __restrict__ x,
                                                 const float* __restrict__ y,
                                                 const float* __restrict__ rnx,
                                                 const float* __restrict__ rny,
                                                 const float* __restrict__ gamma,
                                                 float* __restrict__ costR,
                                                 float* __restrict__ mR) {
  int b = blockIdx.z, mt = blockIdx.y, nt = blockIdx.x;
  int m0 = mt * 32, n0 = nt * 64;
  __shared__ float Xs[16][36];
  __shared__ float Ys[16][68];
  int tid = threadIdx.x;
  int row = tid >> 2, cq = tid & 3;      // staging indices
  int tx = tid & 15, ty = tid >> 4;      // compute: 16x16 grid, 2x4 micro-tile
  const float* xb = x + ((size_t)b * 256 + m0) * 512;
  const float* yb = y + ((size_t)b * 256 + n0) * 512;
  float acc[2][4] = {};
  for (int k0 = 0; k0 < 512; k0 += 16) {
    float4 xv;
    if (tid < 128) xv = *(const float4*)(xb + (size_t)row * 512 + k0 + cq * 4);
    float4 yv = *(const float4*)(yb + (size_t)row * 512 + k0 + cq * 4);
    __syncthreads();
    if (tid < 128) {
      Xs[cq*4+0][row] = xv.x; Xs[cq*4+1][row] = xv.y;
      Xs[cq*4+2][row] = xv.z; Xs[cq*4+3][row] = xv.w;
    }
    Ys[cq*4+0][row] = yv.x; Ys[cq*4+1][row] = yv.y;
    Ys[cq*4+2][row] = yv.z; Ys[cq*4+3][row] = yv.w;
    __syncthreads();
#pragma unroll
    for (int kk = 0; kk < 16; ++kk) {
      float a0 = Xs[kk][ty * 2 + 0];
      float a1 = Xs[kk][ty * 2 + 1];
      float4 bv = *(const float4*)(&Ys[kk][tx * 4]);
      float br[4] = {bv.x, bv.y, bv.z, bv.w};
#pragma unroll
      for (int c = 0; c < 4; ++c) {
        acc[0][c] += a0 * br[c];
        acc[1][c] += a1 * br[c];
      }
    }
  }
  float gv = fmaxf(fabsf(gamma[0]), 1e-4f);
  float ig2 = 1.4426950408889634f / gv;
  float rx[2], ry[4];
#pragma unroll
  for (int r = 0; r < 2; ++r) rx[r] = rnx[b * 256 + m0 + ty * 2 + r];
#pragma unroll
  for (int c = 0; c < 4; ++c) ry[c] = rny[b * 256 + n0 + tx * 4 + c];
  float* cbb = costR + (size_t)b * 65536;
  float* mbb = mR + (size_t)b * 65536;
#pragma unroll
  for (int r = 0; r < 2; ++r) {
    int m = m0 + ty * 2 + r;
    float c0 = (1.0f - acc[r][0] * rx[r] * ry[0]) * ig2;
    float c1 = (1.0f - acc[r][1] * rx[r] * ry[1]) * ig2;
    float c2 = (1.0f - acc[r][2] * rx[r] * ry[2]) * ig2;
    float c3 = (1.0f - acc[r][3] * rx[r] * ry[3]) * ig2;
    float4 stc = {c0, c1, c2, c3};
    float4 stm = {EXP2F(-c0), EXP2F(-c1), EXP2F(-c2), EXP2F(-c3)};
    *(float4*)(cbb + (size_t)m * 256 + n0 + tx * 4) = stc;
    *(float4*)(mbb + (size_t)m * 256 + n0 + tx * 4) = stm;
  }
}

// ---------------------------------------------------------------------------
// Kernel 3: forward soft-DTW in the P-DOMAIN, EPOCH-RENORM variant.
// One wave per batch (8 blocks x 64 -- R11: never share a CU).  Lane l owns
// columns 4l..4l+3, walks rows top->bottom, skewed (lane l does row r at
// slot s = r + l).  True p = P * 2^Q (Q int, constant within each 16-slot
// epoch).  Per slot: 2 shfl + ldexp + 12 arith + float4 P-store -- NO
// transcendentals, NO renorm (R15: the per-slot log2/renorm issue+stall was
// the residual cost).  Renorm + Q bookkeeping once per 16 slots; drift over
// 16 rows bounded by 2^[-47,+26] -- safe in fp32.  q is reconstructed later
// by the parallel weights kernel as q = -Qep - log2(P).
// ---------------------------------------------------------------------------
__global__ void __launch_bounds__(64, 1) fwd_kernel(const float* __restrict__ mR,
                                                    const float* __restrict__ gamma,
                                                    float* __restrict__ PR,
                                                    float* __restrict__ Qep,
                                                    float* __restrict__ dist_out) {
  int b = blockIdx.x, l = threadIdx.x;
  float gv = fmaxf(fabsf(gamma[0]), 1e-4f);
  float gl = gv * 0.6931471805599453f;      // R = q * gl
  const float* mb = mR + (size_t)b * 65536 + 4 * l;
  float* pb = PR + (size_t)b * 65536 + 4 * l;
  float* qe = Qep + ((size_t)b * 64 + l) * 24;   // 21 epochs used, pad to 24
  float P0 = 0.f, P1 = 0.f, P2 = 0.f, P3 = 0.f;  // scaled p of row r-1
  int Q = 0;                                      // lane scale: p = P * 2^Q
  float ucar = (l == 0) ? 1.0f : 0.f;  // p(r-1, 4l-1); origin diag q=0 -> p=1
  float A0[4], A1[4], A2[4], A3[4], A4[4], A5[4], A6[4], A7[4];
  float A8[4], A9[4], A10[4], A11[4], A12[4], A13[4], A14[4], A15[4];
  auto loadC = [&](int s, float* buf) {
    int r = s - l; r = r < 0 ? 0 : (r > 255 ? 255 : r);
    ld4(buf, mb + (size_t)r * 256);
  };
  auto body = [&](int s, const float* mm) {
    int r = s - l;
    bool act = (unsigned)r <= 255u;
    float liP = __shfl_up(P3, 1);
    int   liQ = __shfl_up(Q, 1);
    float li = ldexpf(liP, liQ - Q);   // lane l-1's p(r, 4l-1) at my scale
    if (l == 0) li = 0.0f;
    float n0 = mm[0] * (P0 + li + ucar);
    float n1 = mm[1] * (P1 + n0 + P0);
    float n2 = mm[2] * (P2 + n1 + P1);
    float n3 = mm[3] * (P3 + n2 + P2);
    if (act) {
      float4 st = {n0, n1, n2, n3};
      *(float4*)(pb + (size_t)r * 256) = st;
      P0 = n0; P1 = n1; P2 = n2; P3 = n3;
      ucar = li;
      if (l == 63 && r == 255)
        dist_out[b] = (-(float)Q - LOG2F(n3)) * gl;   // once, off the loop
    }
  };
  loadC(0, A0);  loadC(1, A1);  loadC(2, A2);  loadC(3, A3);
  loadC(4, A4);  loadC(5, A5);  loadC(6, A6);  loadC(7, A7);
  loadC(8, A8);  loadC(9, A9);  loadC(10, A10); loadC(11, A11);
  loadC(12, A12); loadC(13, A13); loadC(14, A14); loadC(15, A15);
  for (int it = 0; it < 21; ++it) {   // 21 epochs x 16 = 336 slots; last live 318
    int s = it * 16;
    qe[it] = (float)Q;                // Q for all rows of this epoch
    body(s + 0,  A0);  loadC(s + 16, A0);
    body(s + 1,  A1);  loadC(s + 17, A1);
    body(s + 2,  A2);  loadC(s + 18, A2);
    body(s + 3,  A3);  loadC(s + 19, A3);
    body(s + 4,  A4);  loadC(s + 20, A4);
    body(s + 5,  A5);  loadC(s + 21, A5);
    body(s + 6,  A6);  loadC(s + 22, A6);
    body(s + 7,  A7);  loadC(s + 23, A7);
    body(s + 8,  A8);  loadC(s + 24, A8);
    body(s + 9,  A9);  loadC(s + 25, A9);
    body(s + 10, A10); loadC(s + 26, A10);
    body(s + 11, A11); loadC(s + 27, A11);
    body(s + 12, A12); loadC(s + 28, A12);
    body(s + 13, A13); loadC(s + 29, A13);
    body(s + 14, A14); loadC(s + 30, A14);
    body(s + 15, A15); loadC(s + 31, A15);
    // Epoch-end renorm -- only if this lane was active at the epoch's last
    // slot (skips pre-active lanes: their P=0 would give a bogus e=-127).
    int rr = s + 15 - l;
    if ((unsigned)rr <= 255u) {
      int e = (int)((__float_as_uint(P3) >> 23) & 255u) - 127;
      P0 = ldexpf(P0, -e); P1 = ldexpf(P1, -e);
      P2 = ldexpf(P2, -e); P3 = ldexpf(P3, -e);
      ucar = ldexpf(ucar, -e);
      Q += e;
    }
  }
}

// ---------------------------------------------------------------------------
// Kernel 3.5: backward weights, PACKED: record[(b*256+r)*64+l] = 16 floats
// (wd[0..3], wn[0..3], wr[0..3], pad) = one aligned 64 B line per (row,lane).
// Reconstructs q = -Qep - log2(P) from the fwd kernel's p-domain output
// (epoch of (row, lane) = (row + lane) >> 4).  Boundary masking folded in.
// ---------------------------------------------------------------------------
__global__ void __launch_bounds__(256) weights_kernel(const float* __restrict__ PR,
                                                      const float* __restrict__ Qep,
                                                      const float* __restrict__ costR,
                                                      float* __restrict__ W3) {
  int tid = blockIdx.x * 256 + threadIdx.x;   // = ((b*256 + r)*64 + l)
  int l = tid & 63;
  int r = (tid >> 6) & 255;
  int b = tid >> 14;
  const float* pbb = PR + (size_t)b * 65536;
  const float* cbb = costR + (size_t)b * 65536;
  const float* qe0 = Qep + ((size_t)b * 64 + l) * 24;
  const float* qe1 = Qep + ((size_t)b * 64 + min(l + 1, 63)) * 24;
  int rp = min(r + 1, 255);
  int c0i = 4 * l;
  int c4 = min(c0i + 4, 255);
  float P0a[5], P1a[5], c0a[5], c1a[5];
  ld4(P0a, pbb + (size_t)r * 256 + c0i);  P0a[4] = pbb[(size_t)r * 256 + c4];
  ld4(P1a, pbb + (size_t)rp * 256 + c0i); P1a[4] = pbb[(size_t)rp * 256 + c4];
  ld4(c0a, cbb + (size_t)r * 256 + c0i);  c0a[4] = cbb[(size_t)r * 256 + c4];
  ld4(c1a, cbb + (size_t)rp * 256 + c0i); c1a[4] = cbb[(size_t)rp * 256 + c4];
  float Q00 = qe0[(r + l) >> 4];        // lane l,   row r
  float Q10 = qe0[(rp + l) >> 4];       // lane l,   row rp
  float Q01 = qe1[(r + l + 1) >> 4];    // lane l+1, row r   (col c4)
  float Q11 = qe1[(rp + l + 1) >> 4];   // lane l+1, row rp  (col c4)
  float q0a[5], q1a[5];
#pragma unroll
  for (int k = 0; k < 4; ++k) {
    q0a[k] = -Q00 - LOG2F(P0a[k]);
    q1a[k] = -Q10 - LOG2F(P1a[k]);
  }
  q0a[4] = -Q01 - LOG2F(P0a[4]);
  q1a[4] = -Q11 - LOG2F(P1a[4]);
  const float CL = 50.0f * 1.4426950408889634f;
  bool rm = (r < 255);
  float w[16];
#pragma unroll
  for (int k = 0; k < 4; ++k) {
    bool cm = (c0i + k < 255);
    float ad = fminf(fmaxf((q1a[k+1] - c1a[k+1]) - q0a[k], -CL), CL);
    float an = fminf(fmaxf((q1a[k]   - c1a[k])   - q0a[k], -CL), CL);
    float ar = fminf(fmaxf((q0a[k+1] - c0a[k+1]) - q0a[k], -CL), CL);
    w[k]      = (rm && cm) ? EXP2F(ad) : 0.0f;
    w[4 + k]  = rm ? EXP2F(an) : 0.0f;
    w[8 + k]  = cm ? EXP2F(ar) : 0.0f;
    w[12 + k] = 0.0f;
  }
  float* wp = W3 + (size_t)tid * 16;
#pragma unroll
  for (int j = 0; j < 4; ++j) *(float4*)(wp + 4 * j) = *(float4*)(w + 4 * j);
}

// ---------------------------------------------------------------------------
// Kernel 4: backward recurrence, ROW-STRIP mirrored: lane l owns cols
// 4l..4l+3, walks rows bottom->top; lane l does row r at slot s = 318-r-l
// (lane 63 leads).  Per slot: ONE shfl_down, 12 FMAs, one 64 B packed-weight
// record via a 12-DEEP FIFO, one float4 E store DIRECTLY to d_out.
//   E[r][c] = E[r+1][c+1]*wd + E[r+1][c]*wn + E[r][c+1]*wr,  E[255][255]=1.
// ---------------------------------------------------------------------------
__global__ void __launch_bounds__(64, 1) bwd_kernel(const float* __restrict__ W3,
                                                    float* __restrict__ out) {
  int b = blockIdx.x, l = threadIdx.x;
  const float* wb = W3 + ((size_t)b * 16384 + l) * 16;   // + r*1024
  float* ob = out + (size_t)b * 65536 + 4 * l;
  float db0 = 0.f, db1 = 0.f, db2 = 0.f, db3 = 0.f;  // E[r+1][4l+k]
  float o0 = 0.f;       // my last row's col 4l value
  float dcar = 0.f;     // E[r+1][4l+4]
  float F0[16], F1[16], F2[16], F3[16], F4[16], F5[16];
  float F6[16], F7[16], F8[16], F9[16], F10[16], F11[16];
  auto loadW = [&](int s, float* buf) {
    int r = 318 - s - l; r = r < 0 ? 0 : (r > 255 ? 255 : r);
    const float* p = wb + (size_t)r * 1024;
    ld4(buf, p); ld4(buf + 4, p + 4); ld4(buf + 8, p + 8); ld4(buf + 12, p + 12);
  };
  auto body = [&](int s, const float* w) {
    int r = 318 - s - l;
    bool act = (unsigned)r <= 255u;
    float ri = __shfl_down(o0, 1);   // E[r][4l+4] (lane l+1, one slot behind)
    if (l == 63) ri = 0.0f;
    float v3 = w[3] * dcar + w[7] * db3 + w[11] * ri;
    if (l == 63 && r == 255) v3 = 1.0f;     // seed E[255][255]
    float v2 = w[2] * db3 + w[6] * db2 + w[10] * v3;
    float v1 = w[1] * db2 + w[5] * db1 + w[9]  * v2;
    float v0 = w[0] * db1 + w[4] * db0 + w[8]  * v1;
    if (act) {
      float4 st = {v0, v1, v2, v3};
      *(float4*)(ob + (size_t)r * 256) = st;
      db0 = v0; db1 = v1; db2 = v2; db3 = v3;
      o0 = v0; dcar = ri;
    }
  };
  loadW(0, F0); loadW(1, F1); loadW(2, F2); loadW(3, F3);
  loadW(4, F4); loadW(5, F5); loadW(6, F6); loadW(7, F7);
  loadW(8, F8); loadW(9, F9); loadW(10, F10); loadW(11, F11);
  for (int it = 0; it < 28; ++it) {   // 336 slots; last live slot = 318
    int s = it * 12;
    body(s + 0,  F0);  loadW(s + 12, F0);
    body(s + 1,  F1);  loadW(s + 13, F1);
    body(s + 2,  F2);  loadW(s + 14, F2);
    body(s + 3,  F3);  loadW(s + 15, F3);
    body(s + 4,  F4);  loadW(s + 16, F4);
    body(s + 5,  F5);  loadW(s + 17, F5);
    body(s + 6,  F6);  loadW(s + 18, F6);
    body(s + 7,  F7);  loadW(s + 19, F7);
    body(s + 8,  F8);  loadW(s + 20, F8);
    body(s + 9,  F9);  loadW(s + 21, F9);
    body(s + 10, F10); loadW(s + 22, F10);
    body(s + 11, F11); loadW(s + 23, F11);
  }
}

// ---------------------------------------------------------------------------
// Workspace (floats), ~14.8 MB:
//   rnx @ 0 (2048) | rny @ 2048 (2048)
//   costR @ 4096   (8*65536, cost*ig2, row-major)
//   mR             (8*65536, exp2(-cost*ig2), row-major)
//   PR             (8*65536, p-domain mantissas, row-major)
//   Qep            (8*64*24 = 12288, per-lane per-epoch scales)
//   W3             (8*256*64*16 = 2,097,152: packed 64 B weight records)
// Alignment (E) goes straight into d_out from bwd_kernel.
// d_out: alignment [0 .. 524287], distance [524288 .. 524295].
// ---------------------------------------------------------------------------
extern "C" void kernel_launch(void* const* d_in, const int* in_sizes, int n_in,
                              void* d_out, int out_size, void* d_ws, size_t ws_size,
                              hipStream_t stream) {
  const float* x = (const float*)d_in[0];
  const float* y = (const float*)d_in[1];
  const float* gamma = (const float*)d_in[2];
  float* out = (float*)d_out;
  float* ws = (float*)d_ws;

  const size_t MAT = (size_t)8 * 65536;
  float* rnx   = ws;
  float* rny   = ws + 2048;
  float* costR = ws + 4096;
  float* mR    = costR + MAT;
  float* PR    = mR + MAT;
  float* Qep   = PR + MAT;
  float* W3    = Qep + 12288;

  norms_kernel<<<1024, 256, 0, stream>>>(x, y, rnx, rny);
  cost_gemm<<<dim3(4, 8, 8), 256, 0, stream>>>(x, y, rnx, rny, gamma, costR, mR);
  fwd_kernel<<<8, 64, 0, stream>>>(mR, gamma, PR, Qep, out + 524288);
  weights_kernel<<<512, 256, 0, stream>>>(PR, Qep, costR, W3);
  bwd_kernel<<<8, 64, 0, stream>>>(W3, out);
}

// Round 17
// 171.253 us; speedup vs baseline: 2.4466x; 1.0478x over previous
//
#include <hip/hip_runtime.h>

// Problem constants: B=8, M=N=256, D=512
#define INFV 1.0e8f
#define DSTR 320   // diagonal planes per batch (d = r + lane, 0..318, pad 320)

// Raw HW transcendentals: v_exp_f32 is 2^x, v_log_f32 is log2(x).
#define EXP2F(x) __builtin_amdgcn_exp2f(x)
#define LOG2F(x) __builtin_amdgcn_logf(x)

__device__ __forceinline__ void ld4(float d[4], const float* p) {
  float4 v = *(const float4*)p;
  d[0] = v.x; d[1] = v.y; d[2] = v.z; d[3] = v.w;
}

// ---------------------------------------------------------------------------
// Kernel 1: inverse row norms.  rn = 1 / max(||row||, 1e-8)
// ---------------------------------------------------------------------------
__global__ void __launch_bounds__(256) norms_kernel(const float* __restrict__ x,
                                                    const float* __restrict__ y,
                                                    float* __restrict__ rnx,
                                                    float* __restrict__ rny) {
  int g = blockIdx.x * 4 + (threadIdx.x >> 6);
  int lane = threadIdx.x & 63;
  const float* src; float* dst; int row;
  if (g < 2048) { src = x; dst = rnx; row = g; }
  else          { src = y; dst = rny; row = g - 2048; }
  const float* p = src + (size_t)row * 512;
  float4 v0 = *(const float4*)(p + lane * 4);
  float4 v1 = *(const float4*)(p + 256 + lane * 4);
  float s = v0.x*v0.x + v0.y*v0.y + v0.z*v0.z + v0.w*v0.w
          + v1.x*v1.x + v1.y*v1.y + v1.z*v1.z + v1.w*v1.w;
#pragma unroll
  for (int o = 32; o > 0; o >>= 1) s += __shfl_xor(s, o, 64);
  if (lane == 0) dst[row] = 1.0f / fmaxf(sqrtf(s), 1e-8f);
}

// ---------------------------------------------------------------------------
// Kernel 2: cost GEMM, 32x64 tiles (256 blocks).  Outputs:
//   costR[b][m][n] = cost*ig2        row-major (weights kernel, coalesced)
//   mD[b][m + n/4][n] = exp2(-cost*ig2)  DIAGONAL planes (fwd kernel:
//     at slot s the whole wave reads plane s contiguously).
// ---------------------------------------------------------------------------
__global__ void __launch_bounds__(256) cost_gemm(const float* __restrict__ x,
                                                 const float* __restrict__ y,
                                                 const float* __restrict__ rnx,
                                                 const float* __restrict__ rny,
                                                 const float* __restrict__ gamma,
                                                 float* __restrict__ costR,
                                                 float* __restrict__ mD) {
  int b = blockIdx.z, mt = blockIdx.y, nt = blockIdx.x;
  int m0 = mt * 32, n0 = nt * 64;
  __shared__ float Xs[16][36];
  __shared__ float Ys[16][68];
  int tid = threadIdx.x;
  int row = tid >> 2, cq = tid & 3;
  int tx = tid & 15, ty = tid >> 4;
  const float* xb = x + ((size_t)b * 256 + m0) * 512;
  const float* yb = y + ((size_t)b * 256 + n0) * 512;
  float acc[2][4] = {};
  for (int k0 = 0; k0 < 512; k0 += 16) {
    float4 xv;
    if (tid < 128) xv = *(const float4*)(xb + (size_t)row * 512 + k0 + cq * 4);
    float4 yv = *(const float4*)(yb + (size_t)row * 512 + k0 + cq * 4);
    __syncthreads();
    if (tid < 128) {
      Xs[cq*4+0][row] = xv.x; Xs[cq*4+1][row] = xv.y;
      Xs[cq*4+2][row] = xv.z; Xs[cq*4+3][row] = xv.w;
    }
    Ys[cq*4+0][row] = yv.x; Ys[cq*4+1][row] = yv.y;
    Ys[cq*4+2][row] = yv.z; Ys[cq*4+3][row] = yv.w;
    __syncthreads();
#pragma unroll
    for (int kk = 0; kk < 16; ++kk) {
      float a0 = Xs[kk][ty * 2 + 0];
      float a1 = Xs[kk][ty * 2 + 1];
      float4 bv = *(const float4*)(&Ys[kk][tx * 4]);
      float br[4] = {bv.x, bv.y, bv.z, bv.w};
#pragma unroll
      for (int c = 0; c < 4; ++c) {
        acc[0][c] += a0 * br[c];
        acc[1][c] += a1 * br[c];
      }
    }
  }
  float gv = fmaxf(fabsf(gamma[0]), 1e-4f);
  float ig2 = 1.4426950408889634f / gv;
  float rx[2], ry[4];
#pragma unroll
  for (int r = 0; r < 2; ++r) rx[r] = rnx[b * 256 + m0 + ty * 2 + r];
#pragma unroll
  for (int c = 0; c < 4; ++c) ry[c] = rny[b * 256 + n0 + tx * 4 + c];
  float* cbb = costR + (size_t)b * 65536;
  float* mbb = mD + (size_t)b * DSTR * 256;
  int l = nt * 16 + tx;                  // column-group lane index
#pragma unroll
  for (int r = 0; r < 2; ++r) {
    int m = m0 + ty * 2 + r;
    float c0 = (1.0f - acc[r][0] * rx[r] * ry[0]) * ig2;
    float c1 = (1.0f - acc[r][1] * rx[r] * ry[1]) * ig2;
    float c2 = (1.0f - acc[r][2] * rx[r] * ry[2]) * ig2;
    float c3 = (1.0f - acc[r][3] * rx[r] * ry[3]) * ig2;
    float4 stc = {c0, c1, c2, c3};
    float4 stm = {EXP2F(-c0), EXP2F(-c1), EXP2F(-c2), EXP2F(-c3)};
    *(float4*)(cbb + (size_t)m * 256 + n0 + tx * 4) = stc;
    *(float4*)(mbb + (size_t)(m + l) * 256 + 4 * l) = stm;   // diagonal plane
  }
}

// ---------------------------------------------------------------------------
// Kernel 3: forward soft-DTW in the P-DOMAIN, epoch renorm, DIAGONAL I/O.
// One wave per batch.  Lane l owns columns 4l..4l+3, row r at slot s = r+l.
// r + l is constant per slot -> cost load (mD plane s) and P store (pD plane
// s) are single coalesced 1 KB transactions (R16: lane-scattered accesses at
// 64 lines/instr were the slot cost).  p = P * 2^Q, Q constant per 16-slot
// epoch; q reconstructed later by the weights kernel as -Qep - log2(P).
// ---------------------------------------------------------------------------
__global__ void __launch_bounds__(64, 1) fwd_kernel(const float* __restrict__ mD,
                                                    const float* __restrict__ gamma,
                                                    float* __restrict__ pD,
                                                    float* __restrict__ Qep,
                                                    float* __restrict__ dist_out) {
  int b = blockIdx.x, l = threadIdx.x;
  float gv = fmaxf(fabsf(gamma[0]), 1e-4f);
  float gl = gv * 0.6931471805599453f;      // R = q * gl
  const float* mb = mD + (size_t)b * DSTR * 256 + 4 * l;
  float* pb = pD + (size_t)b * DSTR * 256 + 4 * l;
  float* qe = Qep + ((size_t)b * 64 + l) * 24;   // 21 epochs used, pad to 24
  float P0 = 0.f, P1 = 0.f, P2 = 0.f, P3 = 0.f;  // scaled p of row r-1
  int Q = 0;                                      // lane scale: p = P * 2^Q
  float ucar = (l == 0) ? 1.0f : 0.f;  // p(r-1, 4l-1); origin diag q=0 -> p=1
  float A0[4], A1[4], A2[4], A3[4], A4[4], A5[4], A6[4], A7[4];
  float A8[4], A9[4], A10[4], A11[4], A12[4], A13[4], A14[4], A15[4];
  auto loadC = [&](int s, float* buf) {
    int d = s > 318 ? 318 : s;
    ld4(buf, mb + (size_t)d * 256);       // coalesced plane read
  };
  auto body = [&](int s, const float* mm) {
    int r = s - l;
    bool act = (unsigned)r <= 255u;
    float liP = __shfl_up(P3, 1);
    int   liQ = __shfl_up(Q, 1);
    float li = ldexpf(liP, liQ - Q);   // lane l-1's p(r, 4l-1) at my scale
    if (l == 0) li = 0.0f;
    float n0 = mm[0] * (P0 + li + ucar);
    float n1 = mm[1] * (P1 + n0 + P0);
    float n2 = mm[2] * (P2 + n1 + P1);
    float n3 = mm[3] * (P3 + n2 + P2);
    if (act) {
      float4 st = {n0, n1, n2, n3};
      *(float4*)(pb + (size_t)s * 256) = st;   // coalesced plane write
      P0 = n0; P1 = n1; P2 = n2; P3 = n3;
      ucar = li;
      if (l == 63 && r == 255)
        dist_out[b] = (-(float)Q - LOG2F(n3)) * gl;   // once, off the loop
    }
  };
  loadC(0, A0);  loadC(1, A1);  loadC(2, A2);  loadC(3, A3);
  loadC(4, A4);  loadC(5, A5);  loadC(6, A6);  loadC(7, A7);
  loadC(8, A8);  loadC(9, A9);  loadC(10, A10); loadC(11, A11);
  loadC(12, A12); loadC(13, A13); loadC(14, A14); loadC(15, A15);
  for (int it = 0; it < 21; ++it) {   // 21 epochs x 16 = 336 slots; last live 318
    int s = it * 16;
    qe[it] = (float)Q;                // Q for all rows of this epoch
    body(s + 0,  A0);  loadC(s + 16, A0);
    body(s + 1,  A1);  loadC(s + 17, A1);
    body(s + 2,  A2);  loadC(s + 18, A2);
    body(s + 3,  A3);  loadC(s + 19, A3);
    body(s + 4,  A4);  loadC(s + 20, A4);
    body(s + 5,  A5);  loadC(s + 21, A5);
    body(s + 6,  A6);  loadC(s + 22, A6);
    body(s + 7,  A7);  loadC(s + 23, A7);
    body(s + 8,  A8);  loadC(s + 24, A8);
    body(s + 9,  A9);  loadC(s + 25, A9);
    body(s + 10, A10); loadC(s + 26, A10);
    body(s + 11, A11); loadC(s + 27, A11);
    body(s + 12, A12); loadC(s + 28, A12);
    body(s + 13, A13); loadC(s + 29, A13);
    body(s + 14, A14); loadC(s + 30, A14);
    body(s + 15, A15); loadC(s + 31, A15);
    int rr = s + 15 - l;
    if ((unsigned)rr <= 255u) {       // epoch-end renorm (active lanes only)
      int e = (int)((__float_as_uint(P3) >> 23) & 255u) - 127;
      P0 = ldexpf(P0, -e); P1 = ldexpf(P1, -e);
      P2 = ldexpf(P2, -e); P3 = ldexpf(P3, -e);
      ucar = ldexpf(ucar, -e);
      Q += e;
    }
  }
}

// ---------------------------------------------------------------------------
// Kernel 3.5: backward weights -> DIAGONAL 3-plane layout
// w3D[b][d][{wd,wn,wr}][256], d = r + lane: at bwd slot s the whole wave
// reads the 3 planes of d = 318-s coalesced.  Reconstructs
// q = -Qep - log2(P) from the diagonal p-domain output.  P(row R, col C)
// lives at pD[b][R + C/4][C].  Boundary masking folded in (w=0).
// This kernel's own loads/stores are lane-scattered -- absorbed by its
// massive parallelism (512 blocks).
// ---------------------------------------------------------------------------
__global__ void __launch_bounds__(256) weights_kernel(const float* __restrict__ pD,
                                                      const float* __restrict__ Qep,
                                                      const float* __restrict__ costR,
                                                      float* __restrict__ w3D) {
  int tid = blockIdx.x * 256 + threadIdx.x;   // = ((b*256 + r)*64 + l)
  int l = tid & 63;
  int r = (tid >> 6) & 255;
  int b = tid >> 14;
  const float* pbb = pD + (size_t)b * DSTR * 256;
  const float* cbb = costR + (size_t)b * 65536;
  const float* qe0 = Qep + ((size_t)b * 64 + l) * 24;
  const float* qe1 = Qep + ((size_t)b * 64 + min(l + 1, 63)) * 24;
  int rp = min(r + 1, 255);
  int c0i = 4 * l;
  int c4 = min(c0i + 4, 255);
  float P0a[5], P1a[5], c0a[5], c1a[5];
  ld4(P0a, pbb + (size_t)(r + l) * 256 + c0i);
  P0a[4] = pbb[(size_t)(r + (c4 >> 2)) * 256 + c4];
  ld4(P1a, pbb + (size_t)(rp + l) * 256 + c0i);
  P1a[4] = pbb[(size_t)(rp + (c4 >> 2)) * 256 + c4];
  ld4(c0a, cbb + (size_t)r * 256 + c0i);  c0a[4] = cbb[(size_t)r * 256 + c4];
  ld4(c1a, cbb + (size_t)rp * 256 + c0i); c1a[4] = cbb[(size_t)rp * 256 + c4];
  float Q00 = qe0[(r + l) >> 4];        // lane l,   row r
  float Q10 = qe0[(rp + l) >> 4];       // lane l,   row rp
  float Q01 = qe1[(r + l + 1) >> 4];    // lane l+1, row r   (col c4; masked l=63)
  float Q11 = qe1[(rp + l + 1) >> 4];   // lane l+1, row rp
  float q0a[5], q1a[5];
#pragma unroll
  for (int k = 0; k < 4; ++k) {
    q0a[k] = -Q00 - LOG2F(P0a[k]);
    q1a[k] = -Q10 - LOG2F(P1a[k]);
  }
  q0a[4] = -Q01 - LOG2F(P0a[4]);
  q1a[4] = -Q11 - LOG2F(P1a[4]);
  const float CL = 50.0f * 1.4426950408889634f;
  bool rm = (r < 255);
  float w[12];
#pragma unroll
  for (int k = 0; k < 4; ++k) {
    bool cm = (c0i + k < 255);
    float ad = fminf(fmaxf((q1a[k+1] - c1a[k+1]) - q0a[k], -CL), CL);
    float an = fminf(fmaxf((q1a[k]   - c1a[k])   - q0a[k], -CL), CL);
    float ar = fminf(fmaxf((q0a[k+1] - c0a[k+1]) - q0a[k], -CL), CL);
    w[k]     = (rm && cm) ? EXP2F(ad) : 0.0f;
    w[4 + k] = rm ? EXP2F(an) : 0.0f;
    w[8 + k] = cm ? EXP2F(ar) : 0.0f;
  }
  float* wp = w3D + ((size_t)(b * DSTR + (r + l)) * 3) * 256 + c0i;
  *(float4*)(wp)       = *(float4*)(w);
  *(float4*)(wp + 256) = *(float4*)(w + 4);
  *(float4*)(wp + 512) = *(float4*)(w + 8);
}

// ---------------------------------------------------------------------------
// Kernel 4: backward recurrence, diagonal-plane weights.  Lane l owns cols
// 4l..4l+3, walks rows bottom->top; lane l does row r at slot s = 318-r-l
// (d = r+l = 318-s constant per slot).  Per slot: ONE shfl_down, 12 FMAs,
// THREE coalesced 1 KB weight-plane loads (12-deep FIFO), one float4 E
// store DIRECTLY to d_out (row-major -- the one remaining scatter).
//   E[r][c] = E[r+1][c+1]*wd + E[r+1][c]*wn + E[r][c+1]*wr,  E[255][255]=1.
// ---------------------------------------------------------------------------
__global__ void __launch_bounds__(64, 1) bwd_kernel(const float* __restrict__ w3D,
                                                    float* __restrict__ out) {
  int b = blockIdx.x, l = threadIdx.x;
  const float* wB = w3D + (size_t)b * DSTR * 768 + 4 * l;
  float* ob = out + (size_t)b * 65536 + 4 * l;
  float db0 = 0.f, db1 = 0.f, db2 = 0.f, db3 = 0.f;  // E[r+1][4l+k]
  float o0 = 0.f;       // my last row's col 4l value
  float dcar = 0.f;     // E[r+1][4l+4]
  float F0[12], F1[12], F2[12], F3[12], F4[12], F5[12];
  float F6[12], F7[12], F8[12], F9[12], F10[12], F11[12];
  auto loadW = [&](int s, float* buf) {
    int d = 318 - s; d = d < 0 ? 0 : d;
    const float* p = wB + (size_t)d * 768;
    ld4(buf, p); ld4(buf + 4, p + 256); ld4(buf + 8, p + 512);  // coalesced
  };
  auto body = [&](int s, const float* w) {
    int r = 318 - s - l;
    bool act = (unsigned)r <= 255u;
    float ri = __shfl_down(o0, 1);   // E[r][4l+4] (lane l+1, one slot behind)
    if (l == 63) ri = 0.0f;
    float v3 = w[3] * dcar + w[7] * db3 + w[11] * ri;
    if (l == 63 && r == 255) v3 = 1.0f;     // seed E[255][255]
    float v2 = w[2] * db3 + w[6] * db2 + w[10] * v3;
    float v1 = w[1] * db2 + w[5] * db1 + w[9]  * v2;
    float v0 = w[0] * db1 + w[4] * db0 + w[8]  * v1;
    if (act) {
      float4 st = {v0, v1, v2, v3};
      *(float4*)(ob + (size_t)r * 256) = st;
      db0 = v0; db1 = v1; db2 = v2; db3 = v3;
      o0 = v0; dcar = ri;
    }
  };
  loadW(0, F0); loadW(1, F1); loadW(2, F2); loadW(3, F3);
  loadW(4, F4); loadW(5, F5); loadW(6, F6); loadW(7, F7);
  loadW(8, F8); loadW(9, F9); loadW(10, F10); loadW(11, F11);
  for (int it = 0; it < 28; ++it) {   // 336 slots; last live slot = 318
    int s = it * 12;
    body(s + 0,  F0);  loadW(s + 12, F0);
    body(s + 1,  F1);  loadW(s + 13, F1);
    body(s + 2,  F2);  loadW(s + 14, F2);
    body(s + 3,  F3);  loadW(s + 15, F3);
    body(s + 4,  F4);  loadW(s + 16, F4);
    body(s + 5,  F5);  loadW(s + 17, F5);
    body(s + 6,  F6);  loadW(s + 18, F6);
    body(s + 7,  F7);  loadW(s + 19, F7);
    body(s + 8,  F8);  loadW(s + 20, F8);
    body(s + 9,  F9);  loadW(s + 21, F9);
    body(s + 10, F10); loadW(s + 22, F10);
    body(s + 11, F11); loadW(s + 23, F11);
  }
}

// ---------------------------------------------------------------------------
// Workspace (floats), ~15.3 MB:
//   rnx @ 0 (2048) | rny @ 2048 (2048)
//   costR (8*65536, cost*ig2, row-major)
//   mD    (8*320*256, exp2(-cost*ig2), diagonal planes)
//   pD    (8*320*256, p-domain mantissas, diagonal planes)
//   Qep   (8*64*24, per-lane per-epoch scales)
//   w3D   (8*320*3*256, diagonal 3-plane packed weights)
// Alignment (E) goes straight into d_out from bwd_kernel.
// d_out: alignment [0 .. 524287], distance [524288 .. 524295].
// ---------------------------------------------------------------------------
extern "C" void kernel_launch(void* const* d_in, const int* in_sizes, int n_in,
                              void* d_out, int out_size, void* d_ws, size_t ws_size,
                              hipStream_t stream) {
  const float* x = (const float*)d_in[0];
  const float* y = (const float*)d_in[1];
  const float* gamma = (const float*)d_in[2];
  float* out = (float*)d_out;
  float* ws = (float*)d_ws;

  const size_t MAT  = (size_t)8 * 65536;
  const size_t DMAT = (size_t)8 * DSTR * 256;
  float* rnx   = ws;
  float* rny   = ws + 2048;
  float* costR = ws + 4096;
  float* mD    = costR + MAT;
  float* pD    = mD + DMAT;
  float* Qep   = pD + DMAT;
  float* w3D   = Qep + 12288;

  norms_kernel<<<1024, 256, 0, stream>>>(x, y, rnx, rny);
  cost_gemm<<<dim3(4, 8, 8), 256, 0, stream>>>(x, y, rnx, rny, gamma, costR, mD);
  fwd_kernel<<<8, 64, 0, stream>>>(mD, gamma, pD, Qep, out + 524288);
  weights_kernel<<<512, 256, 0, stream>>>(pD, Qep, costR, w3D);
  bwd_kernel<<<8, 64, 0, stream>>>(w3D, out);
}